// Round 1
// baseline (1807.760 us; speedup 1.0000x reference)
//
#include <hip/hip_runtime.h>

#define N_NODES 100000
#define N_EDGES 800000
#define HD 128
#define ED 32
#define FAN 288   // 2*HD + ED
#define NL 3

// ---------- CSR construction ----------

__global__ void count_kernel(const int* __restrict__ dst, int* __restrict__ deg) {
    int e = blockIdx.x * 256 + threadIdx.x;
    if (e < N_EDGES) atomicAdd(&deg[dst[e]], 1);
}

// single-block exclusive scan, 1024 threads x 8 elems/chunk
__global__ void scan_kernel(const int* __restrict__ deg, int* __restrict__ ptr,
                            int* __restrict__ cursor, int n) {
    __shared__ int wsum[16];
    __shared__ int s_running;
    const int tid = threadIdx.x;
    const int lane = tid & 63;
    const int wid = tid >> 6;
    if (tid == 0) s_running = 0;
    __syncthreads();
    for (int base = 0; base < n; base += 8192) {
        int v[8]; int tsum = 0;
        int i0 = base + tid * 8;
        #pragma unroll
        for (int j = 0; j < 8; ++j) {
            int i = i0 + j;
            v[j] = (i < n) ? deg[i] : 0;
            tsum += v[j];
        }
        int s = tsum;
        #pragma unroll
        for (int off = 1; off < 64; off <<= 1) {
            int t = __shfl_up(s, off, 64);
            if (lane >= off) s += t;
        }
        if (lane == 63) wsum[wid] = s;
        __syncthreads();
        int wave_off = 0, chunk_total = 0;
        #pragma unroll
        for (int w = 0; w < 16; ++w) {
            int wv = wsum[w];
            if (w < wid) wave_off += wv;
            chunk_total += wv;
        }
        int run = s_running;
        int excl = run + wave_off + (s - tsum);
        #pragma unroll
        for (int j = 0; j < 8; ++j) {
            int i = i0 + j;
            if (i < n) { ptr[i] = excl; cursor[i] = excl; }
            excl += v[j];
        }
        __syncthreads();
        if (tid == 0) s_running = run + chunk_total;
        __syncthreads();
    }
    if (tid == 0) ptr[n] = s_running;
}

__global__ void fill_kernel(const int* __restrict__ src, const int* __restrict__ dst,
                            int* __restrict__ cursor, int* __restrict__ csr_src,
                            int* __restrict__ csr_eid) {
    int e = blockIdx.x * 256 + threadIdx.x;
    if (e < N_EDGES) {
        int d = dst[e];
        int slot = atomicAdd(&cursor[d], 1);
        csr_src[slot] = src[e];
        csr_eid[slot] = e;
    }
}

// per-node: agg_e = sum of edge_attr over in-edges; degf = in-degree (float)
__global__ void node_pre_kernel(const int* __restrict__ ptr, const int* __restrict__ csr_eid,
                                const float* __restrict__ eattr,
                                float* __restrict__ agg_e, float* __restrict__ degf) {
    int node = blockIdx.x * 8 + (threadIdx.x >> 5);
    int f = threadIdx.x & 31;
    if (node >= N_NODES) return;
    int s0 = ptr[node], s1 = ptr[node + 1];
    float acc = 0.f;
    for (int s = s0; s < s1; ++s) {
        int e = csr_eid[s];
        acc += eattr[(size_t)e * ED + f];
    }
    agg_e[(size_t)node * ED + f] = acc;
    if (f == 0) degf[node] = (float)(s1 - s0);
}

// per-layer: agg_src[i] = sum over in-edges of x[src_e]   (32 lanes/node, float4)
__global__ void aggregate_kernel(const int* __restrict__ ptr, const int* __restrict__ csr_src,
                                 const float* __restrict__ x, float* __restrict__ agg) {
    int node = blockIdx.x * 8 + (threadIdx.x >> 5);
    int q = threadIdx.x & 31;
    if (node >= N_NODES) return;
    int s0 = ptr[node], s1 = ptr[node + 1];
    float4 acc = make_float4(0.f, 0.f, 0.f, 0.f);
    for (int s = s0; s < s1; ++s) {
        int sn = csr_src[s];
        float4 vv = *reinterpret_cast<const float4*>(x + (size_t)sn * HD + q * 4);
        acc.x += vv.x; acc.y += vv.y; acc.z += vv.z; acc.w += vv.w;
    }
    *reinterpret_cast<float4*>(agg + (size_t)node * HD + q * 4) = acc;
}

// fused GEMM: out[i,h] = leaky( W[h,0:128]@agg_src[i] + deg_i*(W[h,128:256]@x[i])
//                               + W[h,256:288]@agg_e[i] + deg_i*b[h] )
#define BM 64
#define BK 32

__global__ __launch_bounds__(256) void gemm_kernel(
    const float* __restrict__ x, const float* __restrict__ agg_src,
    const float* __restrict__ agg_e, const float* __restrict__ degf,
    const float* __restrict__ W, const float* __restrict__ b,
    float* __restrict__ out, int last)
{
    __shared__ __align__(16) float As[BK][BM + 4];   // 32 x 68
    __shared__ __align__(16) float Ws[BK][HD + 4];   // 32 x 132
    const int tid = threadIdx.x;
    const int m0 = blockIdx.x * BM;
    const int tr = tid >> 4, tc = tid & 15;
    float acc[4][8] = {};

    for (int kt = 0; kt < FAN / BK; ++kt) {
        __syncthreads();
        // stage A tile: 64 rows x 32 k  (concat source, deg-scaled middle segment)
        #pragma unroll
        for (int r = 0; r < 8; ++r) {
            int idx = r * 256 + tid;
            int kk = idx & 31;
            int row = idx >> 5;
            int grow = m0 + row;
            int k = kt * BK + kk;
            float v = 0.f;
            if (grow < N_NODES) {
                if (k < HD)            v = agg_src[(size_t)grow * HD + k];
                else if (k < 2 * HD)   v = x[(size_t)grow * HD + (k - HD)] * degf[grow];
                else                   v = agg_e[(size_t)grow * ED + (k - 2 * HD)];
            }
            As[kk][row] = v;
        }
        // stage W tile: 128 h x 32 k
        #pragma unroll
        for (int r = 0; r < 16; ++r) {
            int idx = r * 256 + tid;
            int kk = idx & 31;
            int h = idx >> 5;
            Ws[kk][h] = W[(size_t)h * FAN + kt * BK + kk];
        }
        __syncthreads();
        #pragma unroll
        for (int kk = 0; kk < BK; ++kk) {
            float4 a4 = *reinterpret_cast<const float4*>(&As[kk][tr * 4]);
            float4 w0 = *reinterpret_cast<const float4*>(&Ws[kk][tc * 8]);
            float4 w1 = *reinterpret_cast<const float4*>(&Ws[kk][tc * 8 + 4]);
            float a[4]  = {a4.x, a4.y, a4.z, a4.w};
            float wv[8] = {w0.x, w0.y, w0.z, w0.w, w1.x, w1.y, w1.z, w1.w};
            #pragma unroll
            for (int mi = 0; mi < 4; ++mi)
                #pragma unroll
                for (int ni = 0; ni < 8; ++ni)
                    acc[mi][ni] += a[mi] * wv[ni];
        }
    }

    #pragma unroll
    for (int mi = 0; mi < 4; ++mi) {
        int row = m0 + tr * 4 + mi;
        if (row >= N_NODES) continue;
        float dg = degf[row];
        float o[8];
        #pragma unroll
        for (int ni = 0; ni < 8; ++ni) {
            float v = acc[mi][ni] + dg * b[tc * 8 + ni];
            v = (v >= 0.f) ? v : 0.01f * v;
            if (last) v = (v >= 0.f) ? v : 0.01f * v;   // activate_last: leaky applied twice
            o[ni] = v;
        }
        float4* po = reinterpret_cast<float4*>(out + (size_t)row * HD + tc * 8);
        po[0] = make_float4(o[0], o[1], o[2], o[3]);
        po[1] = make_float4(o[4], o[5], o[6], o[7]);
    }
}

extern "C" void kernel_launch(void* const* d_in, const int* in_sizes, int n_in,
                              void* d_out, int out_size, void* d_ws, size_t ws_size,
                              hipStream_t stream) {
    const float* x_in  = (const float*)d_in[0];
    const int*   ei    = (const int*)d_in[1];      // [2, E]: row0 src, row1 dst
    const float* eattr = (const float*)d_in[2];
    const float* Wm    = (const float*)d_in[3];    // [3, 128, 288]
    const float* bm    = (const float*)d_in[4];    // [3, 128]
    float* out = (float*)d_out;

    char* ws = (char*)d_ws;
    size_t off = 0;
    auto alloc = [&](size_t bytes) -> void* {
        void* p = ws + off;
        off = (off + bytes + 255) & ~(size_t)255;
        return p;
    };
    float* agg_src = (float*)alloc((size_t)N_NODES * HD * 4);
    float* x_a     = (float*)alloc((size_t)N_NODES * HD * 4);
    float* agg_e   = (float*)alloc((size_t)N_NODES * ED * 4);
    float* degf    = (float*)alloc((size_t)N_NODES * 4);
    int*   deg     = (int*)alloc((size_t)N_NODES * 4);
    int*   ptr     = (int*)alloc((size_t)(N_NODES + 1) * 4);
    int*   cursor  = (int*)alloc((size_t)N_NODES * 4);
    int*   csr_src = (int*)alloc((size_t)N_EDGES * 4);
    int*   csr_eid = (int*)alloc((size_t)N_EDGES * 4);

    const int* src = ei;
    const int* dst = ei + N_EDGES;

    hipMemsetAsync(deg, 0, (size_t)N_NODES * 4, stream);
    count_kernel<<<(N_EDGES + 255) / 256, 256, 0, stream>>>(dst, deg);
    scan_kernel<<<1, 1024, 0, stream>>>(deg, ptr, cursor, N_NODES);
    fill_kernel<<<(N_EDGES + 255) / 256, 256, 0, stream>>>(src, dst, cursor, csr_src, csr_eid);
    node_pre_kernel<<<(N_NODES + 7) / 8, 256, 0, stream>>>(ptr, csr_eid, eattr, agg_e, degf);

    const float* xcur = x_in;
    float* outs[NL] = {x_a, out, out};   // L2 GEMM is safely in-place (block reads only own rows)
    for (int l = 0; l < NL; ++l) {
        aggregate_kernel<<<(N_NODES + 7) / 8, 256, 0, stream>>>(ptr, csr_src, xcur, agg_src);
        gemm_kernel<<<(N_NODES + BM - 1) / BM, 256, 0, stream>>>(
            xcur, agg_src, agg_e, degf,
            Wm + (size_t)l * HD * FAN, bm + (size_t)l * HD,
            outs[l], (l == NL - 1) ? 1 : 0);
        xcur = outs[l];
    }
}

// Round 2
// 889.533 us; speedup vs baseline: 2.0323x; 2.0323x over previous
//
#include <hip/hip_runtime.h>

#define N_NODES 100000
#define N_EDGES 800000
#define HD 128
#define ED 32
#define FAN 288   // 2*HD + ED
#define NL 3

// ---------- CSR construction ----------

__global__ void count_kernel(const int* __restrict__ dst, int* __restrict__ deg) {
    int e = blockIdx.x * 256 + threadIdx.x;
    if (e < N_EDGES) atomicAdd(&deg[dst[e]], 1);
}

// single-block exclusive scan, 1024 threads x 8 elems/chunk
__global__ void scan_kernel(const int* __restrict__ deg, int* __restrict__ ptr,
                            int* __restrict__ cursor, int n) {
    __shared__ int wsum[16];
    __shared__ int s_running;
    const int tid = threadIdx.x;
    const int lane = tid & 63;
    const int wid = tid >> 6;
    if (tid == 0) s_running = 0;
    __syncthreads();
    for (int base = 0; base < n; base += 8192) {
        int v[8]; int tsum = 0;
        int i0 = base + tid * 8;
        #pragma unroll
        for (int j = 0; j < 8; ++j) {
            int i = i0 + j;
            v[j] = (i < n) ? deg[i] : 0;
            tsum += v[j];
        }
        int s = tsum;
        #pragma unroll
        for (int off = 1; off < 64; off <<= 1) {
            int t = __shfl_up(s, off, 64);
            if (lane >= off) s += t;
        }
        if (lane == 63) wsum[wid] = s;
        __syncthreads();
        int wave_off = 0, chunk_total = 0;
        #pragma unroll
        for (int w = 0; w < 16; ++w) {
            int wv = wsum[w];
            if (w < wid) wave_off += wv;
            chunk_total += wv;
        }
        int run = s_running;
        int excl = run + wave_off + (s - tsum);
        #pragma unroll
        for (int j = 0; j < 8; ++j) {
            int i = i0 + j;
            if (i < n) { ptr[i] = excl; cursor[i] = excl; }
            excl += v[j];
        }
        __syncthreads();
        if (tid == 0) s_running = run + chunk_total;
        __syncthreads();
    }
    if (tid == 0) ptr[n] = s_running;
}

__global__ void fill_kernel(const int* __restrict__ src, const int* __restrict__ dst,
                            int* __restrict__ cursor, int* __restrict__ csr_src,
                            int* __restrict__ csr_eid) {
    int e = blockIdx.x * 256 + threadIdx.x;
    if (e < N_EDGES) {
        int d = dst[e];
        int slot = atomicAdd(&cursor[d], 1);
        csr_src[slot] = src[e];
        csr_eid[slot] = e;
    }
}

// per-node: agg_e = sum of edge_attr over in-edges; degf = in-degree (float)
__global__ void node_pre_kernel(const int* __restrict__ ptr, const int* __restrict__ csr_eid,
                                const float* __restrict__ eattr,
                                float* __restrict__ agg_e, float* __restrict__ degf) {
    int node = blockIdx.x * 8 + (threadIdx.x >> 5);
    int f = threadIdx.x & 31;
    if (node >= N_NODES) return;
    int s0 = ptr[node], s1 = ptr[node + 1];
    float acc = 0.f;
    for (int s = s0; s < s1; ++s) {
        int e = csr_eid[s];
        acc += eattr[(size_t)e * ED + f];
    }
    agg_e[(size_t)node * ED + f] = acc;
    if (f == 0) degf[node] = (float)(s1 - s0);
}

// per-layer: agg_src[i] = sum over in-edges of x[src_e]   (32 lanes/node, float4)
__global__ void aggregate_kernel(const int* __restrict__ ptr, const int* __restrict__ csr_src,
                                 const float* __restrict__ x, float* __restrict__ agg) {
    int node = blockIdx.x * 8 + (threadIdx.x >> 5);
    int q = threadIdx.x & 31;
    if (node >= N_NODES) return;
    int s0 = ptr[node], s1 = ptr[node + 1];
    float4 acc = make_float4(0.f, 0.f, 0.f, 0.f);
    for (int s = s0; s < s1; ++s) {
        int sn = csr_src[s];
        float4 vv = *reinterpret_cast<const float4*>(x + (size_t)sn * HD + q * 4);
        acc.x += vv.x; acc.y += vv.y; acc.z += vv.z; acc.w += vv.w;
    }
    *reinterpret_cast<float4*>(agg + (size_t)node * HD + q * 4) = acc;
}

// transpose W: Wt[l][k][h] = Wm[l][h][k]
__global__ void wt_kernel(const float* __restrict__ Wm, float* __restrict__ Wt) {
    int idx = blockIdx.x * 256 + threadIdx.x;
    if (idx >= NL * FAN * HD) return;
    int l = idx / (FAN * HD);
    int r = idx % (FAN * HD);
    int k = r / HD;
    int h = r % HD;
    Wt[idx] = Wm[(size_t)l * HD * FAN + (size_t)h * FAN + k];
}

// ---------- GEMM: out[i,h] = leaky( A[i,:] @ Wt[:,h] + deg_i*b[h] ) ----------
// A[i,:] = [agg_src[i] | deg_i * x[i] | agg_e[i]]  (staged on the fly)
#define GBM 128
#define GBK 32
#define LDA (GBM + 4)   // 132: stride mod 32 == 4 -> inner reads 2-way (free)

__global__ __launch_bounds__(256) void gemm_kernel(
    const float* __restrict__ agg_src, const float* __restrict__ x,
    const float* __restrict__ agg_e, const float* __restrict__ degf,
    const float* __restrict__ Wt, const float* __restrict__ b,
    float* __restrict__ out, int last)
{
    __shared__ __align__(16) float As[GBK][LDA];
    __shared__ __align__(16) float Ws[GBK][LDA];
    const int tid = threadIdx.x;
    const int m0 = blockIdx.x * GBM;
    const int wid = tid >> 6, lane = tid & 63;
    const int wy = wid >> 1, wx = wid & 1;          // 2x2 waves over 128x128
    const int ly = (lane >> 3) & 7, lx = lane & 7;  // 8x8 lanes over 64x64
    const int row_base = wy * 64 + ly * 8;
    const int col_base = wx * 64 + lx * 8;
    const int srow = tid >> 3;   // 0..31
    const int skg  = tid & 7;    // 0..7

    float acc[8][8] = {};

    for (int kt = 0; kt < FAN / GBK; ++kt) {
        const int k0 = kt * GBK;
        // --- prefetch A tile into regs (3-source concat, wave-uniform branch) ---
        const float* base; int ld; bool scale;
        if (k0 < HD)            { base = agg_src + k0;        ld = HD; scale = false; }
        else if (k0 < 2 * HD)   { base = x + (k0 - HD);       ld = HD; scale = true;  }
        else                    { base = agg_e + (k0 - 2*HD); ld = ED; scale = false; }
        float4 av[4]; float dg[4];
        #pragma unroll
        for (int it = 0; it < 4; ++it) {
            int grow = m0 + srow + it * 32;
            if (grow < N_NODES) {
                av[it] = *reinterpret_cast<const float4*>(base + (size_t)grow * ld + skg * 4);
                dg[it] = scale ? degf[grow] : 1.0f;
            } else { av[it] = make_float4(0.f,0.f,0.f,0.f); dg[it] = 1.0f; }
        }
        // --- prefetch W tile into regs (linear from pre-transposed Wt) ---
        float4 wv[4];
        #pragma unroll
        for (int it = 0; it < 4; ++it) {
            int idx = it * 256 + tid;            // 0..1023
            int kk = idx >> 5, h4 = idx & 31;
            wv[it] = *reinterpret_cast<const float4*>(Wt + (size_t)(k0 + kk) * HD + h4 * 4);
        }
        __syncthreads();   // previous tile fully consumed
        #pragma unroll
        for (int it = 0; it < 4; ++it) {
            int r = srow + it * 32;
            float d = dg[it];
            As[skg * 4 + 0][r] = av[it].x * d;
            As[skg * 4 + 1][r] = av[it].y * d;
            As[skg * 4 + 2][r] = av[it].z * d;
            As[skg * 4 + 3][r] = av[it].w * d;
            int idx = it * 256 + tid;
            int kk = idx >> 5, h4 = idx & 31;
            *reinterpret_cast<float4*>(&Ws[kk][h4 * 4]) = wv[it];
        }
        __syncthreads();
        // --- inner product ---
        #pragma unroll
        for (int kk = 0; kk < GBK; ++kk) {
            float4 a0 = *reinterpret_cast<const float4*>(&As[kk][row_base]);
            float4 a1 = *reinterpret_cast<const float4*>(&As[kk][row_base + 4]);
            float4 w0 = *reinterpret_cast<const float4*>(&Ws[kk][col_base]);
            float4 w1 = *reinterpret_cast<const float4*>(&Ws[kk][col_base + 4]);
            float a[8] = {a0.x,a0.y,a0.z,a0.w,a1.x,a1.y,a1.z,a1.w};
            float w[8] = {w0.x,w0.y,w0.z,w0.w,w1.x,w1.y,w1.z,w1.w};
            #pragma unroll
            for (int i = 0; i < 8; ++i)
                #pragma unroll
                for (int j = 0; j < 8; ++j)
                    acc[i][j] += a[i] * w[j];
        }
    }

    // --- epilogue: + deg*bias, leaky (x2 if last), store ---
    float bv[8];
    #pragma unroll
    for (int j = 0; j < 8; ++j) bv[j] = b[col_base + j];
    #pragma unroll
    for (int i = 0; i < 8; ++i) {
        int row = m0 + row_base + i;
        if (row >= N_NODES) continue;
        float dgr = degf[row];
        float o[8];
        #pragma unroll
        for (int j = 0; j < 8; ++j) {
            float v = acc[i][j] + dgr * bv[j];
            v = (v >= 0.f) ? v : 0.01f * v;
            if (last) v = (v >= 0.f) ? v : 0.01f * v;
            o[j] = v;
        }
        float4* po = reinterpret_cast<float4*>(out + (size_t)row * HD + col_base);
        po[0] = make_float4(o[0], o[1], o[2], o[3]);
        po[1] = make_float4(o[4], o[5], o[6], o[7]);
    }
}

extern "C" void kernel_launch(void* const* d_in, const int* in_sizes, int n_in,
                              void* d_out, int out_size, void* d_ws, size_t ws_size,
                              hipStream_t stream) {
    const float* x_in  = (const float*)d_in[0];
    const int*   ei    = (const int*)d_in[1];      // [2, E]: row0 src, row1 dst
    const float* eattr = (const float*)d_in[2];
    const float* Wm    = (const float*)d_in[3];    // [3, 128, 288]
    const float* bm    = (const float*)d_in[4];    // [3, 128]
    float* out = (float*)d_out;

    char* ws = (char*)d_ws;
    size_t off = 0;
    auto alloc = [&](size_t bytes) -> void* {
        void* p = ws + off;
        off = (off + bytes + 255) & ~(size_t)255;
        return p;
    };
    float* agg_src = (float*)alloc((size_t)N_NODES * HD * 4);
    float* x_a     = (float*)alloc((size_t)N_NODES * HD * 4);
    float* agg_e   = (float*)alloc((size_t)N_NODES * ED * 4);
    float* degf    = (float*)alloc((size_t)N_NODES * 4);
    int*   deg     = (int*)alloc((size_t)N_NODES * 4);
    int*   ptr     = (int*)alloc((size_t)(N_NODES + 1) * 4);
    int*   cursor  = (int*)alloc((size_t)N_NODES * 4);
    int*   csr_src = (int*)alloc((size_t)N_EDGES * 4);
    float* Wt      = (float*)alloc((size_t)NL * FAN * HD * 4);
    // csr_eid aliases x_a: consumed by node_pre before x_a is first written (layer-0 GEMM)
    int*   csr_eid = (int*)x_a;

    const int* src = ei;
    const int* dst = ei + N_EDGES;

    hipMemsetAsync(deg, 0, (size_t)N_NODES * 4, stream);
    count_kernel<<<(N_EDGES + 255) / 256, 256, 0, stream>>>(dst, deg);
    scan_kernel<<<1, 1024, 0, stream>>>(deg, ptr, cursor, N_NODES);
    fill_kernel<<<(N_EDGES + 255) / 256, 256, 0, stream>>>(src, dst, cursor, csr_src, csr_eid);
    node_pre_kernel<<<(N_NODES + 7) / 8, 256, 0, stream>>>(ptr, csr_eid, eattr, agg_e, degf);
    wt_kernel<<<(NL * FAN * HD + 255) / 256, 256, 0, stream>>>(Wm, Wt);

    const float* xcur = x_in;
    float* outs[NL] = {x_a, out, out};   // L2: aggregate consumes d_out before GEMM rewrites it
    for (int l = 0; l < NL; ++l) {
        aggregate_kernel<<<(N_NODES + 7) / 8, 256, 0, stream>>>(ptr, csr_src, xcur, agg_src);
        gemm_kernel<<<(N_NODES + GBM - 1) / GBM, 256, 0, stream>>>(
            agg_src, xcur, agg_e, degf,
            Wt + (size_t)l * FAN * HD, bm + (size_t)l * HD,
            outs[l], (l == NL - 1) ? 1 : 0);
        xcur = outs[l];
    }
}

// Round 3
// 607.916 us; speedup vs baseline: 2.9737x; 1.4632x over previous
//
#include <hip/hip_runtime.h>

#define N_NODES 100000
#define NP      100096   // 782*128, padded so GEMM grid overshoot stays in-bounds
#define N_EDGES 800000
#define HD 128
#define ED 32
#define FAN 288
#define NL 3

typedef short bf16x8 __attribute__((ext_vector_type(8)));
typedef short bf16x4 __attribute__((ext_vector_type(4)));
typedef float f32x4  __attribute__((ext_vector_type(4)));

__device__ inline float b2f(short s) {
    unsigned u = ((unsigned)(unsigned short)s) << 16;
    return __builtin_bit_cast(float, u);
}
__device__ inline short f2b(float f) {   // RTN-even
    unsigned u = __builtin_bit_cast(unsigned, f);
    unsigned r = u + 0x7FFFu + ((u >> 16) & 1u);
    return (short)(r >> 16);
}

// ---------- CSR construction ----------

__global__ void count_kernel(const int* __restrict__ dst, int* __restrict__ deg) {
    int e = blockIdx.x * 256 + threadIdx.x;
    if (e < N_EDGES) atomicAdd(&deg[dst[e]], 1);
}

__global__ void scan_kernel(const int* __restrict__ deg, int* __restrict__ ptr,
                            int* __restrict__ cursor, int n) {
    __shared__ int wsum[16];
    __shared__ int s_running;
    const int tid = threadIdx.x;
    const int lane = tid & 63;
    const int wid = tid >> 6;
    if (tid == 0) s_running = 0;
    __syncthreads();
    for (int base = 0; base < n; base += 8192) {
        int v[8]; int tsum = 0;
        int i0 = base + tid * 8;
        #pragma unroll
        for (int j = 0; j < 8; ++j) {
            int i = i0 + j;
            v[j] = (i < n) ? deg[i] : 0;
            tsum += v[j];
        }
        int s = tsum;
        #pragma unroll
        for (int off = 1; off < 64; off <<= 1) {
            int t = __shfl_up(s, off, 64);
            if (lane >= off) s += t;
        }
        if (lane == 63) wsum[wid] = s;
        __syncthreads();
        int wave_off = 0, chunk_total = 0;
        #pragma unroll
        for (int w = 0; w < 16; ++w) {
            int wv = wsum[w];
            if (w < wid) wave_off += wv;
            chunk_total += wv;
        }
        int run = s_running;
        int excl = run + wave_off + (s - tsum);
        #pragma unroll
        for (int j = 0; j < 8; ++j) {
            int i = i0 + j;
            if (i < n) { ptr[i] = excl; cursor[i] = excl; }
            excl += v[j];
        }
        __syncthreads();
        if (tid == 0) s_running = run + chunk_total;
        __syncthreads();
    }
    if (tid == 0) ptr[n] = s_running;
}

__global__ void fill_kernel(const int* __restrict__ src, const int* __restrict__ dst,
                            int* __restrict__ cursor, int* __restrict__ csr_src,
                            int* __restrict__ csr_eid) {
    int e = blockIdx.x * 256 + threadIdx.x;
    if (e < N_EDGES) {
        int d = dst[e];
        int slot = atomicAdd(&cursor[d], 1);
        csr_src[slot] = src[e];
        csr_eid[slot] = e;
    }
}

// per-node: agg_e (bf16) = sum of edge_attr over in-edges; degf = in-degree
__global__ void node_pre_kernel(const int* __restrict__ ptr, const int* __restrict__ csr_eid,
                                const float* __restrict__ eattr,
                                short* __restrict__ agg_e, float* __restrict__ degf) {
    int node = blockIdx.x * 8 + (threadIdx.x >> 5);
    int f = threadIdx.x & 31;
    if (node >= N_NODES) return;
    int s0 = ptr[node], s1 = ptr[node + 1];
    float acc = 0.f;
    for (int s = s0; s < s1; ++s) {
        int e = csr_eid[s];
        acc += eattr[(size_t)e * ED + f];
    }
    agg_e[(size_t)node * ED + f] = f2b(acc);
    if (f == 0) degf[node] = (float)(s1 - s0);
}

// W (f32 [3][128][288]) -> bf16 same layout
__global__ void wconv_kernel(const float* __restrict__ Wm, short* __restrict__ Wb) {
    int idx = blockIdx.x * 256 + threadIdx.x;
    if (idx < NL * HD * FAN) Wb[idx] = f2b(Wm[idx]);
}

// x_in (f32) -> x_bf16 and xdeg_bf16 = bf16(deg * b2f(x_bf16))
__global__ void xconv_kernel(const float* __restrict__ x, const float* __restrict__ degf,
                             short* __restrict__ xb, short* __restrict__ xd) {
    int i4 = blockIdx.x * 256 + threadIdx.x;
    if (i4 >= N_NODES * (HD / 4)) return;
    int row = i4 >> 5;
    float d = degf[row];
    float4 v = reinterpret_cast<const float4*>(x)[i4];
    bf16x4 o, od;
    float vv[4] = {v.x, v.y, v.z, v.w};
    #pragma unroll
    for (int j = 0; j < 4; ++j) {
        short s = f2b(vv[j]);
        o[j] = s;
        od[j] = f2b(b2f(s) * d);
    }
    *reinterpret_cast<bf16x4*>(xb + (size_t)i4 * 4) = o;
    *reinterpret_cast<bf16x4*>(xd + (size_t)i4 * 4) = od;
}

// per-layer gather-sum: agg[i] = bf16( sum_{e: dst=i} b2f(x_bf16[src_e]) )
// 16 lanes per node, short8 (16B) per lane
__global__ void aggregate_kernel(const int* __restrict__ ptr, const int* __restrict__ csr_src,
                                 const short* __restrict__ x, short* __restrict__ agg) {
    int node = blockIdx.x * 16 + (threadIdx.x >> 4);
    int g = threadIdx.x & 15;
    if (node >= N_NODES) return;
    int s0 = ptr[node], s1 = ptr[node + 1];
    float acc[8] = {};
    for (int s = s0; s < s1; ++s) {
        int sn = csr_src[s];
        bf16x8 v = *reinterpret_cast<const bf16x8*>(x + (size_t)sn * HD + g * 8);
        #pragma unroll
        for (int j = 0; j < 8; ++j) acc[j] += b2f(v[j]);
    }
    bf16x8 o;
    #pragma unroll
    for (int j = 0; j < 8; ++j) o[j] = f2b(acc[j]);
    *reinterpret_cast<bf16x8*>(agg + (size_t)node * HD + g * 8) = o;
}

// ---------- zero-LDS MFMA GEMM ----------
// out[i,h] = leaky( sum_k A[i,k] * W[h,k] + deg_i * b[h] ),
// A[i,:] = [agg_src | xdeg | agg_e] (all bf16, row-major, k-contiguous)
// Block: 256 thr = 4 waves (2x2), tile 128 rows x 128 cols; wave = 64x64.
// mfma_f32_16x16x32_bf16 frags: A/B lane l: row/col = l&15, k = (l>>4)*8 + j.
// D lane l: col = l&15, row = (l>>4)*4 + j.
__global__ __launch_bounds__(256) void gemm_mfma(
    const short* __restrict__ aggs,   // [NP][128]
    const short* __restrict__ xdeg,   // [NP][128]
    const short* __restrict__ agge,   // [NP][32]
    const float* __restrict__ degf,   // [NP]
    const short* __restrict__ Wb,     // [128][288]
    const float* __restrict__ b,      // [128]
    float* __restrict__ out_f32,      // last layer
    short* __restrict__ out_x,        // intermediate: x_bf16 (in-place ok: row-local)
    short* __restrict__ out_xd,       // intermediate: deg*x bf16
    int last)
{
    const int tid = threadIdx.x;
    const int w = tid >> 6, lane = tid & 63;
    const int wy = w >> 1, wx = w & 1;
    const int m0 = blockIdx.x * 128;
    const int l15 = lane & 15, lq = lane >> 4;
    const int kb = lq * 8;
    const size_t arow = (size_t)(m0 + wy * 64 + l15);

    f32x4 acc[4][4];
    #pragma unroll
    for (int i = 0; i < 4; ++i)
        #pragma unroll
        for (int j = 0; j < 4; ++j) acc[i][j] = (f32x4){0.f, 0.f, 0.f, 0.f};

    #pragma unroll
    for (int kt = 0; kt < 9; ++kt) {
        const short* abase;
        int ld, ko;
        if (kt < 4)      { abase = aggs; ld = HD; ko = kt * 32; }
        else if (kt < 8) { abase = xdeg; ld = HD; ko = kt * 32 - 128; }
        else             { abase = agge; ld = ED; ko = 0; }

        bf16x8 a[4], bf[4];
        #pragma unroll
        for (int mf = 0; mf < 4; ++mf)
            a[mf] = *reinterpret_cast<const bf16x8*>(
                abase + (arow + (size_t)mf * 16) * ld + ko + kb);
        #pragma unroll
        for (int nf = 0; nf < 4; ++nf) {
            int c = wx * 64 + nf * 16 + l15;
            bf[nf] = *reinterpret_cast<const bf16x8*>(
                Wb + (size_t)c * FAN + kt * 32 + kb);
        }
        #pragma unroll
        for (int mf = 0; mf < 4; ++mf)
            #pragma unroll
            for (int nf = 0; nf < 4; ++nf)
                acc[mf][nf] = __builtin_amdgcn_mfma_f32_16x16x32_bf16(
                    a[mf], bf[nf], acc[mf][nf], 0, 0, 0);
    }

    // epilogue
    #pragma unroll
    for (int mf = 0; mf < 4; ++mf) {
        int r0 = m0 + wy * 64 + mf * 16 + lq * 4;
        float dg[4];
        #pragma unroll
        for (int j = 0; j < 4; ++j)
            dg[j] = (r0 + j < N_NODES) ? degf[r0 + j] : 0.f;
        #pragma unroll
        for (int nf = 0; nf < 4; ++nf) {
            int c = wx * 64 + nf * 16 + l15;
            float bc = b[c];
            #pragma unroll
            for (int j = 0; j < 4; ++j) {
                int row = r0 + j;
                if (row >= N_NODES) continue;
                float v = acc[mf][nf][j] + dg[j] * bc;
                v = (v >= 0.f) ? v : 0.01f * v;
                if (last) {
                    v = (v >= 0.f) ? v : 0.01f * v;   // activate_last
                    out_f32[(size_t)row * HD + c] = v;
                } else {
                    short xb = f2b(v);
                    out_x[(size_t)row * HD + c] = xb;
                    out_xd[(size_t)row * HD + c] = f2b(b2f(xb) * dg[j]);
                }
            }
        }
    }
}

extern "C" void kernel_launch(void* const* d_in, const int* in_sizes, int n_in,
                              void* d_out, int out_size, void* d_ws, size_t ws_size,
                              hipStream_t stream) {
    const float* x_in  = (const float*)d_in[0];
    const int*   ei    = (const int*)d_in[1];
    const float* eattr = (const float*)d_in[2];
    const float* Wm    = (const float*)d_in[3];
    const float* bm    = (const float*)d_in[4];
    float* out = (float*)d_out;

    char* ws = (char*)d_ws;
    size_t off = 0;
    auto alloc = [&](size_t bytes) -> void* {
        void* p = ws + off;
        off = (off + bytes + 255) & ~(size_t)255;
        return p;
    };
    short* x_bf   = (short*)alloc((size_t)NP * HD * 2);
    short* xdeg   = (short*)alloc((size_t)NP * HD * 2);
    short* aggs   = (short*)alloc((size_t)NP * HD * 2);
    short* agge   = (short*)alloc((size_t)NP * ED * 2);
    float* degf   = (float*)alloc((size_t)NP * 4);
    int*   deg    = (int*)alloc((size_t)N_NODES * 4);
    int*   ptr    = (int*)alloc((size_t)(N_NODES + 1) * 4);
    int*   cursor = (int*)alloc((size_t)N_NODES * 4);
    int*   csr_src= (int*)alloc((size_t)N_EDGES * 4);
    int*   csr_eid= (int*)alloc((size_t)N_EDGES * 4);
    short* Wb     = (short*)alloc((size_t)NL * HD * FAN * 2);

    const int* src = ei;
    const int* dst = ei + N_EDGES;

    hipMemsetAsync(deg, 0, (size_t)N_NODES * 4, stream);
    count_kernel<<<(N_EDGES + 255) / 256, 256, 0, stream>>>(dst, deg);
    scan_kernel<<<1, 1024, 0, stream>>>(deg, ptr, cursor, N_NODES);
    fill_kernel<<<(N_EDGES + 255) / 256, 256, 0, stream>>>(src, dst, cursor, csr_src, csr_eid);
    node_pre_kernel<<<(N_NODES + 7) / 8, 256, 0, stream>>>(ptr, csr_eid, eattr, agge, degf);
    wconv_kernel<<<(NL * HD * FAN + 255) / 256, 256, 0, stream>>>(Wm, Wb);
    xconv_kernel<<<(N_NODES * (HD / 4) + 255) / 256, 256, 0, stream>>>(x_in, degf, x_bf, xdeg);

    for (int l = 0; l < NL; ++l) {
        aggregate_kernel<<<(N_NODES + 15) / 16, 256, 0, stream>>>(ptr, csr_src, x_bf, aggs);
        gemm_mfma<<<NP / 128, 256, 0, stream>>>(
            aggs, xdeg, agge, degf,
            Wb + (size_t)l * HD * FAN, bm + (size_t)l * HD,
            out, x_bf, xdeg, (l == NL - 1) ? 1 : 0);
    }
}

// Round 4
// 480.385 us; speedup vs baseline: 3.7631x; 1.2655x over previous
//
#include <hip/hip_runtime.h>

#define N_NODES 100000
#define NP      100096   // 782*128, padded so GEMM grid overshoot stays in-bounds
#define N_EDGES 800000
#define HD 128
#define ED 32
#define FAN 288
#define NL 3

#define SCHUNK 2048                     // 256 thr * 8 elems
#define SBLK   ((N_NODES + SCHUNK - 1) / SCHUNK)   // 49

typedef short bf16x8 __attribute__((ext_vector_type(8)));
typedef short bf16x4 __attribute__((ext_vector_type(4)));
typedef float f32x4  __attribute__((ext_vector_type(4)));

__device__ inline float b2f(short s) {
    unsigned u = ((unsigned)(unsigned short)s) << 16;
    return __builtin_bit_cast(float, u);
}
__device__ inline short f2b(float f) {   // RTN-even
    unsigned u = __builtin_bit_cast(unsigned, f);
    unsigned r = u + 0x7FFFu + ((u >> 16) & 1u);
    return (short)(r >> 16);
}

// ---------- CSR construction ----------

__global__ void count_kernel(const int* __restrict__ dst, int* __restrict__ deg) {
    int e = blockIdx.x * 256 + threadIdx.x;
    if (e < N_EDGES) atomicAdd(&deg[dst[e]], 1);
}

// phase 1: per-block chunk sums
__global__ void scan_reduce(const int* __restrict__ deg, int* __restrict__ bsum) {
    __shared__ int ws[4];
    const int tid = threadIdx.x;
    int i0 = blockIdx.x * SCHUNK + tid * 8;
    int t = 0;
    #pragma unroll
    for (int j = 0; j < 8; ++j) {
        int i = i0 + j;
        if (i < N_NODES) t += deg[i];
    }
    #pragma unroll
    for (int off = 32; off >= 1; off >>= 1) t += __shfl_down(t, off, 64);
    if ((tid & 63) == 0) ws[tid >> 6] = t;
    __syncthreads();
    if (tid == 0) bsum[blockIdx.x] = ws[0] + ws[1] + ws[2] + ws[3];
}

// phase 2: one wave scans SBLK partials -> exclusive boff, total -> ptr[N_NODES]
__global__ void scan_mid(const int* __restrict__ bsum, int* __restrict__ boff,
                         int* __restrict__ ptr) {
    int lane = threadIdx.x;
    int v = (lane < SBLK) ? bsum[lane] : 0;
    int s = v;
    #pragma unroll
    for (int off = 1; off < 64; off <<= 1) {
        int t = __shfl_up(s, off, 64);
        if (lane >= off) s += t;
    }
    if (lane < SBLK) boff[lane] = s - v;
    if (lane == 63) ptr[N_NODES] = s;
}

// phase 3: in-chunk exclusive scan + block offset -> ptr, cursor
__global__ void scan_final(const int* __restrict__ deg, const int* __restrict__ boff,
                           int* __restrict__ ptr, int* __restrict__ cursor) {
    __shared__ int wsum[4];
    const int tid = threadIdx.x;
    const int lane = tid & 63, wid = tid >> 6;
    int i0 = blockIdx.x * SCHUNK + tid * 8;
    int v[8]; int tsum = 0;
    #pragma unroll
    for (int j = 0; j < 8; ++j) {
        int i = i0 + j;
        v[j] = (i < N_NODES) ? deg[i] : 0;
        tsum += v[j];
    }
    int s = tsum;
    #pragma unroll
    for (int off = 1; off < 64; off <<= 1) {
        int t = __shfl_up(s, off, 64);
        if (lane >= off) s += t;
    }
    if (lane == 63) wsum[wid] = s;
    __syncthreads();
    int woff = 0;
    #pragma unroll
    for (int w = 0; w < 4; ++w) if (w < wid) woff += wsum[w];
    int excl = boff[blockIdx.x] + woff + (s - tsum);
    #pragma unroll
    for (int j = 0; j < 8; ++j) {
        int i = i0 + j;
        if (i < N_NODES) { ptr[i] = excl; cursor[i] = excl; }
        excl += v[j];
    }
}

__global__ void fill_kernel(const int* __restrict__ src, const int* __restrict__ dst,
                            int* __restrict__ cursor, int* __restrict__ csr_src,
                            int* __restrict__ csr_eid) {
    int e = blockIdx.x * 256 + threadIdx.x;
    if (e < N_EDGES) {
        int d = dst[e];
        int slot = atomicAdd(&cursor[d], 1);
        csr_src[slot] = src[e];
        csr_eid[slot] = e;
    }
}

// per-node: agg_e (bf16) = sum of edge_attr over in-edges; degf = in-degree
__global__ void node_pre_kernel(const int* __restrict__ ptr, const int* __restrict__ csr_eid,
                                const float* __restrict__ eattr,
                                short* __restrict__ agg_e, float* __restrict__ degf) {
    int node = blockIdx.x * 8 + (threadIdx.x >> 5);
    int f = threadIdx.x & 31;
    if (node >= N_NODES) return;
    int s0 = ptr[node], s1 = ptr[node + 1];
    float acc = 0.f;
    for (int s = s0; s < s1; ++s) {
        int e = csr_eid[s];
        acc += eattr[(size_t)e * ED + f];
    }
    agg_e[(size_t)node * ED + f] = f2b(acc);
    if (f == 0) degf[node] = (float)(s1 - s0);
}

// W (f32 [3][128][288]) -> bf16 same layout
__global__ void wconv_kernel(const float* __restrict__ Wm, short* __restrict__ Wb) {
    int idx = blockIdx.x * 256 + threadIdx.x;
    if (idx < NL * HD * FAN) Wb[idx] = f2b(Wm[idx]);
}

// x_in (f32) -> x_bf16 and xdeg_bf16 = bf16(deg * b2f(x_bf16))
__global__ void xconv_kernel(const float* __restrict__ x, const float* __restrict__ degf,
                             short* __restrict__ xb, short* __restrict__ xd) {
    int i4 = blockIdx.x * 256 + threadIdx.x;
    if (i4 >= N_NODES * (HD / 4)) return;
    int row = i4 >> 5;
    float d = degf[row];
    float4 v = reinterpret_cast<const float4*>(x)[i4];
    bf16x4 o, od;
    float vv[4] = {v.x, v.y, v.z, v.w};
    #pragma unroll
    for (int j = 0; j < 4; ++j) {
        short s = f2b(vv[j]);
        o[j] = s;
        od[j] = f2b(b2f(s) * d);
    }
    *reinterpret_cast<bf16x4*>(xb + (size_t)i4 * 4) = o;
    *reinterpret_cast<bf16x4*>(xd + (size_t)i4 * 4) = od;
}

// per-layer gather-sum: agg[i] = bf16( sum_{e: dst=i} b2f(x_bf16[src_e]) )
__global__ void aggregate_kernel(const int* __restrict__ ptr, const int* __restrict__ csr_src,
                                 const short* __restrict__ x, short* __restrict__ agg) {
    int node = blockIdx.x * 16 + (threadIdx.x >> 4);
    int g = threadIdx.x & 15;
    if (node >= N_NODES) return;
    int s0 = ptr[node], s1 = ptr[node + 1];
    float acc[8] = {};
    for (int s = s0; s < s1; ++s) {
        int sn = csr_src[s];
        bf16x8 v = *reinterpret_cast<const bf16x8*>(x + (size_t)sn * HD + g * 8);
        #pragma unroll
        for (int j = 0; j < 8; ++j) acc[j] += b2f(v[j]);
    }
    bf16x8 o;
    #pragma unroll
    for (int j = 0; j < 8; ++j) o[j] = f2b(acc[j]);
    *reinterpret_cast<bf16x8*>(agg + (size_t)node * HD + g * 8) = o;
}

// ---------- zero-LDS MFMA GEMM ----------
__global__ __launch_bounds__(256) void gemm_mfma(
    const short* __restrict__ aggs,   // [NP][128]
    const short* __restrict__ xdeg,   // [NP][128]
    const short* __restrict__ agge,   // [NP][32]
    const float* __restrict__ degf,   // [NP]
    const short* __restrict__ Wb,     // [128][288]
    const float* __restrict__ b,      // [128]
    float* __restrict__ out_f32,      // last layer
    short* __restrict__ out_x,        // intermediate: x_bf16 (in-place ok: row-local)
    short* __restrict__ out_xd,       // intermediate: deg*x bf16
    int last)
{
    const int tid = threadIdx.x;
    const int w = tid >> 6, lane = tid & 63;
    const int wy = w >> 1, wx = w & 1;
    const int m0 = blockIdx.x * 128;
    const int l15 = lane & 15, lq = lane >> 4;
    const int kb = lq * 8;
    const size_t arow = (size_t)(m0 + wy * 64 + l15);

    f32x4 acc[4][4];
    #pragma unroll
    for (int i = 0; i < 4; ++i)
        #pragma unroll
        for (int j = 0; j < 4; ++j) acc[i][j] = (f32x4){0.f, 0.f, 0.f, 0.f};

    #pragma unroll
    for (int kt = 0; kt < 9; ++kt) {
        const short* abase;
        int ld, ko;
        if (kt < 4)      { abase = aggs; ld = HD; ko = kt * 32; }
        else if (kt < 8) { abase = xdeg; ld = HD; ko = kt * 32 - 128; }
        else             { abase = agge; ld = ED; ko = 0; }

        bf16x8 a[4], bf[4];
        #pragma unroll
        for (int mf = 0; mf < 4; ++mf)
            a[mf] = *reinterpret_cast<const bf16x8*>(
                abase + (arow + (size_t)mf * 16) * ld + ko + kb);
        #pragma unroll
        for (int nf = 0; nf < 4; ++nf) {
            int c = wx * 64 + nf * 16 + l15;
            bf[nf] = *reinterpret_cast<const bf16x8*>(
                Wb + (size_t)c * FAN + kt * 32 + kb);
        }
        #pragma unroll
        for (int mf = 0; mf < 4; ++mf)
            #pragma unroll
            for (int nf = 0; nf < 4; ++nf)
                acc[mf][nf] = __builtin_amdgcn_mfma_f32_16x16x32_bf16(
                    a[mf], bf[nf], acc[mf][nf], 0, 0, 0);
    }

    // epilogue
    #pragma unroll
    for (int mf = 0; mf < 4; ++mf) {
        int r0 = m0 + wy * 64 + mf * 16 + lq * 4;
        float dg[4];
        #pragma unroll
        for (int j = 0; j < 4; ++j)
            dg[j] = (r0 + j < N_NODES) ? degf[r0 + j] : 0.f;
        #pragma unroll
        for (int nf = 0; nf < 4; ++nf) {
            int c = wx * 64 + nf * 16 + l15;
            float bc = b[c];
            #pragma unroll
            for (int j = 0; j < 4; ++j) {
                int row = r0 + j;
                if (row >= N_NODES) continue;
                float v = acc[mf][nf][j] + dg[j] * bc;
                v = (v >= 0.f) ? v : 0.01f * v;
                if (last) {
                    v = (v >= 0.f) ? v : 0.01f * v;   // activate_last
                    out_f32[(size_t)row * HD + c] = v;
                } else {
                    short xb = f2b(v);
                    out_x[(size_t)row * HD + c] = xb;
                    out_xd[(size_t)row * HD + c] = f2b(b2f(xb) * dg[j]);
                }
            }
        }
    }
}

extern "C" void kernel_launch(void* const* d_in, const int* in_sizes, int n_in,
                              void* d_out, int out_size, void* d_ws, size_t ws_size,
                              hipStream_t stream) {
    const float* x_in  = (const float*)d_in[0];
    const int*   ei    = (const int*)d_in[1];
    const float* eattr = (const float*)d_in[2];
    const float* Wm    = (const float*)d_in[3];
    const float* bm    = (const float*)d_in[4];
    float* out = (float*)d_out;

    char* ws = (char*)d_ws;
    size_t off = 0;
    auto alloc = [&](size_t bytes) -> void* {
        void* p = ws + off;
        off = (off + bytes + 255) & ~(size_t)255;
        return p;
    };
    short* x_bf   = (short*)alloc((size_t)NP * HD * 2);
    short* xdeg   = (short*)alloc((size_t)NP * HD * 2);
    short* aggs   = (short*)alloc((size_t)NP * HD * 2);
    short* agge   = (short*)alloc((size_t)NP * ED * 2);
    float* degf   = (float*)alloc((size_t)NP * 4);
    int*   deg    = (int*)alloc((size_t)N_NODES * 4);
    int*   ptr    = (int*)alloc((size_t)(N_NODES + 1) * 4);
    int*   cursor = (int*)alloc((size_t)N_NODES * 4);
    int*   csr_src= (int*)alloc((size_t)N_EDGES * 4);
    int*   csr_eid= (int*)alloc((size_t)N_EDGES * 4);
    short* Wb     = (short*)alloc((size_t)NL * HD * FAN * 2);
    int*   bsum   = (int*)alloc((size_t)SBLK * 4);
    int*   boff   = (int*)alloc((size_t)SBLK * 4);

    const int* src = ei;
    const int* dst = ei + N_EDGES;

    hipMemsetAsync(deg, 0, (size_t)N_NODES * 4, stream);
    count_kernel<<<(N_EDGES + 255) / 256, 256, 0, stream>>>(dst, deg);
    scan_reduce<<<SBLK, 256, 0, stream>>>(deg, bsum);
    scan_mid<<<1, 64, 0, stream>>>(bsum, boff, ptr);
    scan_final<<<SBLK, 256, 0, stream>>>(deg, boff, ptr, cursor);
    fill_kernel<<<(N_EDGES + 255) / 256, 256, 0, stream>>>(src, dst, cursor, csr_src, csr_eid);
    node_pre_kernel<<<(N_NODES + 7) / 8, 256, 0, stream>>>(ptr, csr_eid, eattr, agge, degf);
    wconv_kernel<<<(NL * HD * FAN + 255) / 256, 256, 0, stream>>>(Wm, Wb);
    xconv_kernel<<<(N_NODES * (HD / 4) + 255) / 256, 256, 0, stream>>>(x_in, degf, x_bf, xdeg);

    for (int l = 0; l < NL; ++l) {
        aggregate_kernel<<<(N_NODES + 15) / 16, 256, 0, stream>>>(ptr, csr_src, x_bf, aggs);
        gemm_mfma<<<NP / 128, 256, 0, stream>>>(
            aggs, xdeg, agge, degf,
            Wb + (size_t)l * HD * FAN, bm + (size_t)l * HD,
            out, x_bf, xdeg, (l == NL - 1) ? 1 : 0);
    }
}

// Round 5
// 422.887 us; speedup vs baseline: 4.2748x; 1.1360x over previous
//
#include <hip/hip_runtime.h>

#define N_NODES 100000
#define NP      100096   // 782*128, padded so GEMM grid overshoot stays in-bounds
#define N_EDGES 800000
#define HD 128
#define ED 32
#define FAN 288
#define NL 3

#define SCHUNK 2048                     // 256 thr * 8 elems
#define SBLK   ((N_NODES + SCHUNK - 1) / SCHUNK)   // 49

typedef short bf16x8 __attribute__((ext_vector_type(8)));
typedef short bf16x4 __attribute__((ext_vector_type(4)));
typedef float f32x4  __attribute__((ext_vector_type(4)));

__device__ inline float b2f(short s) {
    unsigned u = ((unsigned)(unsigned short)s) << 16;
    return __builtin_bit_cast(float, u);
}
__device__ inline short f2b(float f) {   // RTN-even
    unsigned u = __builtin_bit_cast(unsigned, f);
    unsigned r = u + 0x7FFFu + ((u >> 16) & 1u);
    return (short)(r >> 16);
}

// ---------- CSR construction ----------

__global__ void count_kernel(const int* __restrict__ dst, int* __restrict__ deg) {
    int e = blockIdx.x * 256 + threadIdx.x;
    if (e < N_EDGES) atomicAdd(&deg[dst[e]], 1);
}

__global__ void scan_reduce(const int* __restrict__ deg, int* __restrict__ bsum) {
    __shared__ int ws[4];
    const int tid = threadIdx.x;
    int i0 = blockIdx.x * SCHUNK + tid * 8;
    int t = 0;
    #pragma unroll
    for (int j = 0; j < 8; ++j) {
        int i = i0 + j;
        if (i < N_NODES) t += deg[i];
    }
    #pragma unroll
    for (int off = 32; off >= 1; off >>= 1) t += __shfl_down(t, off, 64);
    if ((tid & 63) == 0) ws[tid >> 6] = t;
    __syncthreads();
    if (tid == 0) bsum[blockIdx.x] = ws[0] + ws[1] + ws[2] + ws[3];
}

__global__ void scan_mid(const int* __restrict__ bsum, int* __restrict__ boff,
                         int* __restrict__ ptr) {
    int lane = threadIdx.x;
    int v = (lane < SBLK) ? bsum[lane] : 0;
    int s = v;
    #pragma unroll
    for (int off = 1; off < 64; off <<= 1) {
        int t = __shfl_up(s, off, 64);
        if (lane >= off) s += t;
    }
    if (lane < SBLK) boff[lane] = s - v;
    if (lane == 63) ptr[N_NODES] = s;
}

__global__ void scan_final(const int* __restrict__ deg, const int* __restrict__ boff,
                           int* __restrict__ ptr, int* __restrict__ cursor) {
    __shared__ int wsum[4];
    const int tid = threadIdx.x;
    const int lane = tid & 63, wid = tid >> 6;
    int i0 = blockIdx.x * SCHUNK + tid * 8;
    int v[8]; int tsum = 0;
    #pragma unroll
    for (int j = 0; j < 8; ++j) {
        int i = i0 + j;
        v[j] = (i < N_NODES) ? deg[i] : 0;
        tsum += v[j];
    }
    int s = tsum;
    #pragma unroll
    for (int off = 1; off < 64; off <<= 1) {
        int t = __shfl_up(s, off, 64);
        if (lane >= off) s += t;
    }
    if (lane == 63) wsum[wid] = s;
    __syncthreads();
    int woff = 0;
    #pragma unroll
    for (int w = 0; w < 4; ++w) if (w < wid) woff += wsum[w];
    int excl = boff[blockIdx.x] + woff + (s - tsum);
    #pragma unroll
    for (int j = 0; j < 8; ++j) {
        int i = i0 + j;
        if (i < N_NODES) { ptr[i] = excl; cursor[i] = excl; }
        excl += v[j];
    }
}

// one int2 (src, eid) scatter per edge
__global__ void fill_kernel(const int* __restrict__ src, const int* __restrict__ dst,
                            int* __restrict__ cursor, int2* __restrict__ csr2) {
    int e = blockIdx.x * 256 + threadIdx.x;
    if (e < N_EDGES) {
        int d = dst[e];
        int slot = atomicAdd(&cursor[d], 1);
        csr2[slot] = make_int2(src[e], e);
    }
}

// phase A: chain-free edge-parallel permute eattr -> CSR order, bf16
// 8 lanes per slot, float4 read / bf16x4 write
__global__ void permute_eattr(const int2* __restrict__ csr2, const float* __restrict__ eattr,
                              short* __restrict__ ecsr) {
    int idx = blockIdx.x * 256 + threadIdx.x;
    int s = idx >> 3;
    int g = idx & 7;
    if (s >= N_EDGES) return;
    int e = csr2[s].y;
    float4 v = *reinterpret_cast<const float4*>(eattr + (size_t)e * ED + g * 4);
    bf16x4 o;
    o[0] = f2b(v.x); o[1] = f2b(v.y); o[2] = f2b(v.z); o[3] = f2b(v.w);
    *reinterpret_cast<bf16x4*>(ecsr + (size_t)s * ED + g * 4) = o;
}

// phase B: node-parallel sequential segment-sum (affine addresses, no chains)
// 8 lanes per node; also writes degf
__global__ void edge_sum(const short* __restrict__ ecsr, const int* __restrict__ ptr,
                         short* __restrict__ agge, float* __restrict__ degf) {
    int node = blockIdx.x * 32 + (threadIdx.x >> 3);
    int g = threadIdx.x & 7;
    if (node >= N_NODES) return;
    int s0 = ptr[node], s1 = ptr[node + 1];
    float a[4] = {};
    for (int s = s0; s < s1; ++s) {
        bf16x4 v = *reinterpret_cast<const bf16x4*>(ecsr + (size_t)s * ED + g * 4);
        #pragma unroll
        for (int j = 0; j < 4; ++j) a[j] += b2f(v[j]);
    }
    bf16x4 o;
    #pragma unroll
    for (int j = 0; j < 4; ++j) o[j] = f2b(a[j]);
    *reinterpret_cast<bf16x4*>(agge + (size_t)node * ED + g * 4) = o;
    if (g == 0) degf[node] = (float)(s1 - s0);
}

// W (f32 [3][128][288]) -> bf16 same layout
__global__ void wconv_kernel(const float* __restrict__ Wm, short* __restrict__ Wb) {
    int idx = blockIdx.x * 256 + threadIdx.x;
    if (idx < NL * HD * FAN) Wb[idx] = f2b(Wm[idx]);
}

// x_in (f32) -> x_bf16 and xdeg_bf16 = bf16(deg * b2f(x_bf16))
__global__ void xconv_kernel(const float* __restrict__ x, const float* __restrict__ degf,
                             short* __restrict__ xb, short* __restrict__ xd) {
    int i4 = blockIdx.x * 256 + threadIdx.x;
    if (i4 >= N_NODES * (HD / 4)) return;
    int row = i4 >> 5;
    float d = degf[row];
    float4 v = reinterpret_cast<const float4*>(x)[i4];
    bf16x4 o, od;
    float vv[4] = {v.x, v.y, v.z, v.w};
    #pragma unroll
    for (int j = 0; j < 4; ++j) {
        short s = f2b(vv[j]);
        o[j] = s;
        od[j] = f2b(b2f(s) * d);
    }
    *reinterpret_cast<bf16x4*>(xb + (size_t)i4 * 4) = o;
    *reinterpret_cast<bf16x4*>(xd + (size_t)i4 * 4) = od;
}

// per-layer gather-sum, software-pipelined 2-wide:
// agg[i] = bf16( sum_{e: dst=i} b2f(x[src_e]) ), 16 lanes/node, bf16x8 rows
__global__ void aggregate_kernel(const int* __restrict__ ptr, const int2* __restrict__ csr2,
                                 const short* __restrict__ x, short* __restrict__ agg) {
    int node = blockIdx.x * 16 + (threadIdx.x >> 4);
    int g = threadIdx.x & 15;
    if (node >= N_NODES) return;
    int s0 = ptr[node], s1 = ptr[node + 1];
    float acc0[8] = {}, acc1[8] = {};
    int s = s0;
    int i0 = (s < s1) ? csr2[s].x : 0;
    int i1 = (s + 1 < s1) ? csr2[s + 1].x : 0;
    for (; s + 2 <= s1;) {
        bf16x8 v0 = *reinterpret_cast<const bf16x8*>(x + (size_t)i0 * HD + g * 8);
        bf16x8 v1 = *reinterpret_cast<const bf16x8*>(x + (size_t)i1 * HD + g * 8);
        s += 2;
        i0 = (s < s1) ? csr2[s].x : 0;
        i1 = (s + 1 < s1) ? csr2[s + 1].x : 0;
        #pragma unroll
        for (int j = 0; j < 8; ++j) acc0[j] += b2f(v0[j]);
        #pragma unroll
        for (int j = 0; j < 8; ++j) acc1[j] += b2f(v1[j]);
    }
    if (s < s1) {
        bf16x8 v0 = *reinterpret_cast<const bf16x8*>(x + (size_t)i0 * HD + g * 8);
        #pragma unroll
        for (int j = 0; j < 8; ++j) acc0[j] += b2f(v0[j]);
    }
    bf16x8 o;
    #pragma unroll
    for (int j = 0; j < 8; ++j) o[j] = f2b(acc0[j] + acc1[j]);
    *reinterpret_cast<bf16x8*>(agg + (size_t)node * HD + g * 8) = o;
}

// ---------- zero-LDS MFMA GEMM ----------
__global__ __launch_bounds__(256) void gemm_mfma(
    const short* __restrict__ aggs,   // [NP][128]
    const short* __restrict__ xdeg,   // [NP][128]
    const short* __restrict__ agge,   // [NP][32]
    const float* __restrict__ degf,   // [NP]
    const short* __restrict__ Wb,     // [128][288]
    const float* __restrict__ b,      // [128]
    float* __restrict__ out_f32,      // last layer
    short* __restrict__ out_x,        // intermediate: x_bf16 (in-place ok: row-local)
    short* __restrict__ out_xd,       // intermediate: deg*x bf16
    int last)
{
    const int tid = threadIdx.x;
    const int w = tid >> 6, lane = tid & 63;
    const int wy = w >> 1, wx = w & 1;
    const int m0 = blockIdx.x * 128;
    const int l15 = lane & 15, lq = lane >> 4;
    const int kb = lq * 8;
    const size_t arow = (size_t)(m0 + wy * 64 + l15);

    f32x4 acc[4][4];
    #pragma unroll
    for (int i = 0; i < 4; ++i)
        #pragma unroll
        for (int j = 0; j < 4; ++j) acc[i][j] = (f32x4){0.f, 0.f, 0.f, 0.f};

    #pragma unroll
    for (int kt = 0; kt < 9; ++kt) {
        const short* abase;
        int ld, ko;
        if (kt < 4)      { abase = aggs; ld = HD; ko = kt * 32; }
        else if (kt < 8) { abase = xdeg; ld = HD; ko = kt * 32 - 128; }
        else             { abase = agge; ld = ED; ko = 0; }

        bf16x8 a[4], bf[4];
        #pragma unroll
        for (int mf = 0; mf < 4; ++mf)
            a[mf] = *reinterpret_cast<const bf16x8*>(
                abase + (arow + (size_t)mf * 16) * ld + ko + kb);
        #pragma unroll
        for (int nf = 0; nf < 4; ++nf) {
            int c = wx * 64 + nf * 16 + l15;
            bf[nf] = *reinterpret_cast<const bf16x8*>(
                Wb + (size_t)c * FAN + kt * 32 + kb);
        }
        #pragma unroll
        for (int mf = 0; mf < 4; ++mf)
            #pragma unroll
            for (int nf = 0; nf < 4; ++nf)
                acc[mf][nf] = __builtin_amdgcn_mfma_f32_16x16x32_bf16(
                    a[mf], bf[nf], acc[mf][nf], 0, 0, 0);
    }

    // epilogue
    #pragma unroll
    for (int mf = 0; mf < 4; ++mf) {
        int r0 = m0 + wy * 64 + mf * 16 + lq * 4;
        float dg[4];
        #pragma unroll
        for (int j = 0; j < 4; ++j)
            dg[j] = (r0 + j < N_NODES) ? degf[r0 + j] : 0.f;
        #pragma unroll
        for (int nf = 0; nf < 4; ++nf) {
            int c = wx * 64 + nf * 16 + l15;
            float bc = b[c];
            #pragma unroll
            for (int j = 0; j < 4; ++j) {
                int row = r0 + j;
                if (row >= N_NODES) continue;
                float v = acc[mf][nf][j] + dg[j] * bc;
                v = (v >= 0.f) ? v : 0.01f * v;
                if (last) {
                    v = (v >= 0.f) ? v : 0.01f * v;   // activate_last
                    out_f32[(size_t)row * HD + c] = v;
                } else {
                    short xb = f2b(v);
                    out_x[(size_t)row * HD + c] = xb;
                    out_xd[(size_t)row * HD + c] = f2b(b2f(xb) * dg[j]);
                }
            }
        }
    }
}

extern "C" void kernel_launch(void* const* d_in, const int* in_sizes, int n_in,
                              void* d_out, int out_size, void* d_ws, size_t ws_size,
                              hipStream_t stream) {
    const float* x_in  = (const float*)d_in[0];
    const int*   ei    = (const int*)d_in[1];
    const float* eattr = (const float*)d_in[2];
    const float* Wm    = (const float*)d_in[3];
    const float* bm    = (const float*)d_in[4];
    float* out = (float*)d_out;

    char* ws = (char*)d_ws;
    size_t off = 0;
    auto alloc = [&](size_t bytes) -> void* {
        void* p = ws + off;
        off = (off + bytes + 255) & ~(size_t)255;
        return p;
    };
    short* x_bf   = (short*)alloc((size_t)NP * HD * 2);
    short* xdeg   = (short*)alloc((size_t)NP * HD * 2);
    short* aggs   = (short*)alloc((size_t)NP * HD * 2);
    short* agge   = (short*)alloc((size_t)NP * ED * 2);
    float* degf   = (float*)alloc((size_t)NP * 4);
    int*   deg    = (int*)alloc((size_t)N_NODES * 4);
    int*   ptr    = (int*)alloc((size_t)(N_NODES + 1) * 4);
    int*   cursor = (int*)alloc((size_t)N_NODES * 4);
    int2*  csr2   = (int2*)alloc((size_t)N_EDGES * 8);
    short* Wb     = (short*)alloc((size_t)NL * HD * FAN * 2);
    int*   bsum   = (int*)alloc((size_t)SBLK * 4);
    int*   boff   = (int*)alloc((size_t)SBLK * 4);

    // ecsr (800K x 32 bf16 = 51.2 MB) aliases x_bf+xdeg (51.25 MB contiguous):
    // fully consumed by edge_sum before xconv writes x_bf/xdeg.
    short* ecsr = x_bf;

    const int* src = ei;
    const int* dst = ei + N_EDGES;

    hipMemsetAsync(deg, 0, (size_t)N_NODES * 4, stream);
    count_kernel<<<(N_EDGES + 255) / 256, 256, 0, stream>>>(dst, deg);
    scan_reduce<<<SBLK, 256, 0, stream>>>(deg, bsum);
    scan_mid<<<1, 64, 0, stream>>>(bsum, boff, ptr);
    scan_final<<<SBLK, 256, 0, stream>>>(deg, boff, ptr, cursor);
    fill_kernel<<<(N_EDGES + 255) / 256, 256, 0, stream>>>(src, dst, cursor, csr2);
    permute_eattr<<<(N_EDGES * 8 + 255) / 256, 256, 0, stream>>>(csr2, eattr, ecsr);
    edge_sum<<<(N_NODES + 31) / 32, 256, 0, stream>>>(ecsr, ptr, agge, degf);
    wconv_kernel<<<(NL * HD * FAN + 255) / 256, 256, 0, stream>>>(Wm, Wb);
    xconv_kernel<<<(N_NODES * (HD / 4) + 255) / 256, 256, 0, stream>>>(x_in, degf, x_bf, xdeg);

    for (int l = 0; l < NL; ++l) {
        aggregate_kernel<<<(N_NODES + 15) / 16, 256, 0, stream>>>(ptr, csr2, x_bf, aggs);
        gemm_mfma<<<NP / 128, 256, 0, stream>>>(
            aggs, xdeg, agge, degf,
            Wb + (size_t)l * HD * FAN, bm + (size_t)l * HD,
            out, x_bf, xdeg, (l == NL - 1) ? 1 : 0);
    }
}

// Round 6
// 372.906 us; speedup vs baseline: 4.8478x; 1.1340x over previous
//
#include <hip/hip_runtime.h>

#define N_NODES 100000
#define NP      100096   // multiple of 128 and 64; pad rows guarded
#define N_EDGES 800000
#define HD 128
#define ED 32
#define FAN 288
#define NL 3

#define SCHUNK 2048
#define SBLK   ((N_NODES + SCHUNK - 1) / SCHUNK)   // 49

typedef short bf16x8 __attribute__((ext_vector_type(8)));
typedef short bf16x4 __attribute__((ext_vector_type(4)));
typedef float f32x4  __attribute__((ext_vector_type(4)));

__device__ inline float b2f(short s) {
    unsigned u = ((unsigned)(unsigned short)s) << 16;
    return __builtin_bit_cast(float, u);
}
__device__ inline short f2b(float f) {   // RTN-even
    unsigned u = __builtin_bit_cast(unsigned, f);
    unsigned r = u + 0x7FFFu + ((u >> 16) & 1u);
    return (short)(r >> 16);
}

// ---------- CSR construction ----------

__global__ void count_kernel(const int* __restrict__ dst, int* __restrict__ deg) {
    int e = blockIdx.x * 256 + threadIdx.x;
    if (e < N_EDGES) atomicAdd(&deg[dst[e]], 1);
}

__global__ void scan_reduce(const int* __restrict__ deg, int* __restrict__ bsum) {
    __shared__ int ws[4];
    const int tid = threadIdx.x;
    int i0 = blockIdx.x * SCHUNK + tid * 8;
    int t = 0;
    #pragma unroll
    for (int j = 0; j < 8; ++j) {
        int i = i0 + j;
        if (i < N_NODES) t += deg[i];
    }
    #pragma unroll
    for (int off = 32; off >= 1; off >>= 1) t += __shfl_down(t, off, 64);
    if ((tid & 63) == 0) ws[tid >> 6] = t;
    __syncthreads();
    if (tid == 0) bsum[blockIdx.x] = ws[0] + ws[1] + ws[2] + ws[3];
}

__global__ void scan_mid(const int* __restrict__ bsum, int* __restrict__ boff,
                         int* __restrict__ ptr) {
    int lane = threadIdx.x;
    int v = (lane < SBLK) ? bsum[lane] : 0;
    int s = v;
    #pragma unroll
    for (int off = 1; off < 64; off <<= 1) {
        int t = __shfl_up(s, off, 64);
        if (lane >= off) s += t;
    }
    if (lane < SBLK) boff[lane] = s - v;
    if (lane == 63) ptr[N_NODES] = s;
}

__global__ void scan_final(const int* __restrict__ deg, const int* __restrict__ boff,
                           int* __restrict__ ptr, int* __restrict__ cursor) {
    __shared__ int wsum[4];
    const int tid = threadIdx.x;
    const int lane = tid & 63, wid = tid >> 6;
    int i0 = blockIdx.x * SCHUNK + tid * 8;
    int v[8]; int tsum = 0;
    #pragma unroll
    for (int j = 0; j < 8; ++j) {
        int i = i0 + j;
        v[j] = (i < N_NODES) ? deg[i] : 0;
        tsum += v[j];
    }
    int s = tsum;
    #pragma unroll
    for (int off = 1; off < 64; off <<= 1) {
        int t = __shfl_up(s, off, 64);
        if (lane >= off) s += t;
    }
    if (lane == 63) wsum[wid] = s;
    __syncthreads();
    int woff = 0;
    #pragma unroll
    for (int w = 0; w < 4; ++w) if (w < wid) woff += wsum[w];
    int excl = boff[blockIdx.x] + woff + (s - tsum);
    #pragma unroll
    for (int j = 0; j < 8; ++j) {
        int i = i0 + j;
        if (i < N_NODES) { ptr[i] = excl; cursor[i] = excl; }
        excl += v[j];
    }
}

__global__ void fill_kernel(const int* __restrict__ src, const int* __restrict__ dst,
                            int* __restrict__ cursor, int2* __restrict__ csr2) {
    int e = blockIdx.x * 256 + threadIdx.x;
    if (e < N_EDGES) {
        int d = dst[e];
        int slot = atomicAdd(&cursor[d], 1);
        csr2[slot] = make_int2(src[e], e);
    }
}

// chain-free edge-parallel permute eattr -> CSR order, bf16
__global__ void permute_eattr(const int2* __restrict__ csr2, const float* __restrict__ eattr,
                              short* __restrict__ ecsr) {
    int idx = blockIdx.x * 256 + threadIdx.x;
    int s = idx >> 3;
    int g = idx & 7;
    if (s >= N_EDGES) return;
    int e = csr2[s].y;
    float4 v = *reinterpret_cast<const float4*>(eattr + (size_t)e * ED + g * 4);
    bf16x4 o;
    o[0] = f2b(v.x); o[1] = f2b(v.y); o[2] = f2b(v.z); o[3] = f2b(v.w);
    *reinterpret_cast<bf16x4*>(ecsr + (size_t)s * ED + g * 4) = o;
}

// node-parallel sequential segment-sum over CSR-ordered edge attrs
__global__ void edge_sum(const short* __restrict__ ecsr, const int* __restrict__ ptr,
                         short* __restrict__ agge, float* __restrict__ degf) {
    int node = blockIdx.x * 32 + (threadIdx.x >> 3);
    int g = threadIdx.x & 7;
    if (node >= N_NODES) return;
    int s0 = ptr[node], s1 = ptr[node + 1];
    float a[4] = {};
    for (int s = s0; s < s1; ++s) {
        bf16x4 v = *reinterpret_cast<const bf16x4*>(ecsr + (size_t)s * ED + g * 4);
        #pragma unroll
        for (int j = 0; j < 4; ++j) a[j] += b2f(v[j]);
    }
    bf16x4 o;
    #pragma unroll
    for (int j = 0; j < 4; ++j) o[j] = f2b(a[j]);
    *reinterpret_cast<bf16x4*>(agge + (size_t)node * ED + g * 4) = o;
    if (g == 0) degf[node] = (float)(s1 - s0);
}

__global__ void wconv_kernel(const float* __restrict__ Wm, short* __restrict__ Wb) {
    int idx = blockIdx.x * 256 + threadIdx.x;
    if (idx < NL * HD * FAN) Wb[idx] = f2b(Wm[idx]);
}

__global__ void xconv_kernel(const float* __restrict__ x, const float* __restrict__ degf,
                             short* __restrict__ xb, short* __restrict__ xd) {
    int i4 = blockIdx.x * 256 + threadIdx.x;
    if (i4 >= N_NODES * (HD / 4)) return;
    int row = i4 >> 5;
    float d = degf[row];
    float4 v = reinterpret_cast<const float4*>(x)[i4];
    bf16x4 o, od;
    float vv[4] = {v.x, v.y, v.z, v.w};
    #pragma unroll
    for (int j = 0; j < 4; ++j) {
        short s = f2b(vv[j]);
        o[j] = s;
        od[j] = f2b(b2f(s) * d);
    }
    *reinterpret_cast<bf16x4*>(xb + (size_t)i4 * 4) = o;
    *reinterpret_cast<bf16x4*>(xd + (size_t)i4 * 4) = od;
}

// ---------- fused per-layer kernel: gather-aggregate (LDS) + MFMA GEMM ----------
// Block = 64 node-rows, 256 threads (4 waves, 2x2 over 64x128 output tile).
// Phase 1: agg_src rows gathered into XOR-swizzled LDS bf16 tile [64][128].
// Phase 2: out[i,h] = leaky( [LDS agg | xdeg | agge] @ W[h,:] + deg_i*b[h] ).
#define TM 64

__global__ __launch_bounds__(256) void fused_layer(
    const int* __restrict__ ptr, const int2* __restrict__ csr2,
    const short* __restrict__ xprev,  // [NP][128] bf16 (gather source, read-only)
    const short* __restrict__ xdeg,   // [NP][128] bf16 (own-row read, in-place write OK)
    const short* __restrict__ agge,   // [NP][32]
    const float* __restrict__ degf,   // [NP]
    const short* __restrict__ Wb,     // [128][288]
    const float* __restrict__ b,      // [128]
    float* __restrict__ out_f32,      // last layer
    short* __restrict__ out_x,        // next-layer x (ping-pong, != xprev)
    short* __restrict__ out_xd,       // xdeg (in-place)
    int last)
{
    __shared__ char As[TM * 256];     // 16 KB: [64 rows][128 cols] bf16, swizzled
    const int tid = threadIdx.x;
    const int m0 = blockIdx.x * TM;

    // ---- phase 1: gather-sum into LDS ----
    {
        const int ng = tid >> 4, g = tid & 15;
        #pragma unroll
        for (int i = 0; i < 4; ++i) {
            int row = i * 16 + ng;          // 0..63
            int node = m0 + row;
            float acc0[8] = {}, acc1[8] = {};
            if (node < N_NODES) {
                int s0 = ptr[node], s1 = ptr[node + 1];
                int s = s0;
                int i0 = (s < s1) ? csr2[s].x : 0;
                int i1 = (s + 1 < s1) ? csr2[s + 1].x : 0;
                for (; s + 2 <= s1;) {
                    bf16x8 v0 = *reinterpret_cast<const bf16x8*>(xprev + (size_t)i0 * HD + g * 8);
                    bf16x8 v1 = *reinterpret_cast<const bf16x8*>(xprev + (size_t)i1 * HD + g * 8);
                    s += 2;
                    i0 = (s < s1) ? csr2[s].x : 0;
                    i1 = (s + 1 < s1) ? csr2[s + 1].x : 0;
                    #pragma unroll
                    for (int j = 0; j < 8; ++j) acc0[j] += b2f(v0[j]);
                    #pragma unroll
                    for (int j = 0; j < 8; ++j) acc1[j] += b2f(v1[j]);
                }
                if (s < s1) {
                    bf16x8 v0 = *reinterpret_cast<const bf16x8*>(xprev + (size_t)i0 * HD + g * 8);
                    #pragma unroll
                    for (int j = 0; j < 8; ++j) acc0[j] += b2f(v0[j]);
                }
            }
            bf16x8 o;
            #pragma unroll
            for (int j = 0; j < 8; ++j) o[j] = f2b(acc0[j] + acc1[j]);
            int byte = row * 256 + g * 16;
            byte ^= (row & 7) << 4;         // swizzle: spreads 256B-stride rows over banks
            *reinterpret_cast<bf16x8*>(As + byte) = o;
        }
    }
    __syncthreads();

    // ---- phase 2: MFMA ----
    const int w = tid >> 6, lane = tid & 63;
    const int wy = w >> 1, wx = w & 1;       // wy: row half (32), wx: col half (64)
    const int l15 = lane & 15, lq = lane >> 4;
    const int kb = lq * 8;

    f32x4 acc[2][4];
    #pragma unroll
    for (int i = 0; i < 2; ++i)
        #pragma unroll
        for (int j = 0; j < 4; ++j) acc[i][j] = (f32x4){0.f, 0.f, 0.f, 0.f};

    // kt 0..3: A from LDS (agg_src)
    #pragma unroll
    for (int kt = 0; kt < 4; ++kt) {
        bf16x8 a[2], bf[4];
        #pragma unroll
        for (int mf = 0; mf < 2; ++mf) {
            int row = wy * 32 + mf * 16 + l15;
            int byte = row * 256 + kt * 64 + kb * 2;
            byte ^= (row & 7) << 4;
            a[mf] = *reinterpret_cast<const bf16x8*>(As + byte);
        }
        #pragma unroll
        for (int nf = 0; nf < 4; ++nf) {
            int c = wx * 64 + nf * 16 + l15;
            bf[nf] = *reinterpret_cast<const bf16x8*>(Wb + (size_t)c * FAN + kt * 32 + kb);
        }
        #pragma unroll
        for (int mf = 0; mf < 2; ++mf)
            #pragma unroll
            for (int nf = 0; nf < 4; ++nf)
                acc[mf][nf] = __builtin_amdgcn_mfma_f32_16x16x32_bf16(
                    a[mf], bf[nf], acc[mf][nf], 0, 0, 0);
    }
    // kt 4..7: A from xdeg (own rows, global); kt 8: agge
    #pragma unroll
    for (int kt = 4; kt < 9; ++kt) {
        bf16x8 a[2], bf[4];
        #pragma unroll
        for (int mf = 0; mf < 2; ++mf) {
            size_t arow = (size_t)(m0 + wy * 32 + mf * 16 + l15);
            a[mf] = (kt < 8)
                ? *reinterpret_cast<const bf16x8*>(xdeg + arow * HD + (kt * 32 - 128) + kb)
                : *reinterpret_cast<const bf16x8*>(agge + arow * ED + kb);
        }
        #pragma unroll
        for (int nf = 0; nf < 4; ++nf) {
            int c = wx * 64 + nf * 16 + l15;
            bf[nf] = *reinterpret_cast<const bf16x8*>(Wb + (size_t)c * FAN + kt * 32 + kb);
        }
        #pragma unroll
        for (int mf = 0; mf < 2; ++mf)
            #pragma unroll
            for (int nf = 0; nf < 4; ++nf)
                acc[mf][nf] = __builtin_amdgcn_mfma_f32_16x16x32_bf16(
                    a[mf], bf[nf], acc[mf][nf], 0, 0, 0);
    }

    // ---- epilogue ----
    #pragma unroll
    for (int mf = 0; mf < 2; ++mf) {
        int r0 = m0 + wy * 32 + mf * 16 + lq * 4;
        float dg[4];
        #pragma unroll
        for (int j = 0; j < 4; ++j)
            dg[j] = (r0 + j < N_NODES) ? degf[r0 + j] : 0.f;
        #pragma unroll
        for (int nf = 0; nf < 4; ++nf) {
            int c = wx * 64 + nf * 16 + l15;
            float bc = b[c];
            #pragma unroll
            for (int j = 0; j < 4; ++j) {
                int row = r0 + j;
                if (row >= N_NODES) continue;
                float v = acc[mf][nf][j] + dg[j] * bc;
                v = (v >= 0.f) ? v : 0.01f * v;
                if (last) {
                    v = (v >= 0.f) ? v : 0.01f * v;   // activate_last
                    out_f32[(size_t)row * HD + c] = v;
                } else {
                    short xb = f2b(v);
                    out_x[(size_t)row * HD + c] = xb;
                    out_xd[(size_t)row * HD + c] = f2b(b2f(xb) * dg[j]);
                }
            }
        }
    }
}

extern "C" void kernel_launch(void* const* d_in, const int* in_sizes, int n_in,
                              void* d_out, int out_size, void* d_ws, size_t ws_size,
                              hipStream_t stream) {
    const float* x_in  = (const float*)d_in[0];
    const int*   ei    = (const int*)d_in[1];
    const float* eattr = (const float*)d_in[2];
    const float* Wm    = (const float*)d_in[3];
    const float* bm    = (const float*)d_in[4];
    float* out = (float*)d_out;

    char* ws = (char*)d_ws;
    size_t off = 0;
    auto alloc = [&](size_t bytes) -> void* {
        void* p = ws + off;
        off = (off + bytes + 255) & ~(size_t)255;
        return p;
    };
    short* x0     = (short*)alloc((size_t)NP * HD * 2);
    short* x1     = (short*)alloc((size_t)NP * HD * 2);
    short* xdeg   = (short*)alloc((size_t)NP * HD * 2);
    short* agge   = (short*)alloc((size_t)NP * ED * 2);
    float* degf   = (float*)alloc((size_t)NP * 4);
    int*   deg    = (int*)alloc((size_t)N_NODES * 4);
    int*   ptr    = (int*)alloc((size_t)(N_NODES + 1) * 4);
    int*   cursor = (int*)alloc((size_t)N_NODES * 4);
    int2*  csr2   = (int2*)alloc((size_t)N_EDGES * 8);
    short* Wb     = (short*)alloc((size_t)NL * HD * FAN * 2);
    int*   bsum   = (int*)alloc((size_t)SBLK * 4);
    int*   boff   = (int*)alloc((size_t)SBLK * 4);

    // ecsr (800K x 32 bf16 = 51.2 MB) aliases x0+x1 (51.25 MB contiguous):
    // fully consumed by edge_sum before xconv writes x0 / layer-0 writes x1.
    short* ecsr = x0;

    const int* src = ei;
    const int* dst = ei + N_EDGES;

    hipMemsetAsync(deg, 0, (size_t)N_NODES * 4, stream);
    count_kernel<<<(N_EDGES + 255) / 256, 256, 0, stream>>>(dst, deg);
    scan_reduce<<<SBLK, 256, 0, stream>>>(deg, bsum);
    scan_mid<<<1, 64, 0, stream>>>(bsum, boff, ptr);
    scan_final<<<SBLK, 256, 0, stream>>>(deg, boff, ptr, cursor);
    fill_kernel<<<(N_EDGES + 255) / 256, 256, 0, stream>>>(src, dst, cursor, csr2);
    permute_eattr<<<(N_EDGES * 8 + 255) / 256, 256, 0, stream>>>(csr2, eattr, ecsr);
    edge_sum<<<(N_NODES + 31) / 32, 256, 0, stream>>>(ecsr, ptr, agge, degf);
    wconv_kernel<<<(NL * HD * FAN + 255) / 256, 256, 0, stream>>>(Wm, Wb);
    xconv_kernel<<<(N_NODES * (HD / 4) + 255) / 256, 256, 0, stream>>>(x_in, degf, x0, xdeg);

    short* xping[2] = {x0, x1};
    for (int l = 0; l < NL; ++l) {
        fused_layer<<<NP / TM, 256, 0, stream>>>(
            ptr, csr2, xping[l & 1], xdeg, agge, degf,
            Wb + (size_t)l * HD * FAN, bm + (size_t)l * HD,
            out, xping[(l + 1) & 1], xdeg, (l == NL - 1) ? 1 : 0);
    }
}

// Round 7
// 344.056 us; speedup vs baseline: 5.2543x; 1.0839x over previous
//
#include <hip/hip_runtime.h>

#define N_NODES 100000
#define NP      100096   // multiple of 128/64/32; pad rows guarded
#define N_EDGES 800000
#define HD 128
#define ED 32
#define FAN 288
#define NL 3

#define SCHUNK 2048
#define SBLK   ((N_NODES + SCHUNK - 1) / SCHUNK)   // 49

typedef short bf16x8 __attribute__((ext_vector_type(8)));
typedef short bf16x4 __attribute__((ext_vector_type(4)));
typedef float f32x4  __attribute__((ext_vector_type(4)));

__device__ inline float b2f(short s) {
    unsigned u = ((unsigned)(unsigned short)s) << 16;
    return __builtin_bit_cast(float, u);
}
__device__ inline short f2b(float f) {   // RTN-even
    unsigned u = __builtin_bit_cast(unsigned, f);
    unsigned r = u + 0x7FFFu + ((u >> 16) & 1u);
    return (short)(r >> 16);
}

// ---------- CSR construction ----------

__global__ void count_kernel(const int* __restrict__ dst, int* __restrict__ deg) {
    int e = blockIdx.x * 256 + threadIdx.x;
    if (e < N_EDGES) atomicAdd(&deg[dst[e]], 1);
}

__global__ void scan_reduce(const int* __restrict__ deg, int* __restrict__ bsum) {
    __shared__ int ws[4];
    const int tid = threadIdx.x;
    int i0 = blockIdx.x * SCHUNK + tid * 8;
    int t = 0;
    #pragma unroll
    for (int j = 0; j < 8; ++j) {
        int i = i0 + j;
        if (i < N_NODES) t += deg[i];
    }
    #pragma unroll
    for (int off = 32; off >= 1; off >>= 1) t += __shfl_down(t, off, 64);
    if ((tid & 63) == 0) ws[tid >> 6] = t;
    __syncthreads();
    if (tid == 0) bsum[blockIdx.x] = ws[0] + ws[1] + ws[2] + ws[3];
}

__global__ void scan_mid(const int* __restrict__ bsum, int* __restrict__ boff,
                         int* __restrict__ ptr) {
    int lane = threadIdx.x;
    int v = (lane < SBLK) ? bsum[lane] : 0;
    int s = v;
    #pragma unroll
    for (int off = 1; off < 64; off <<= 1) {
        int t = __shfl_up(s, off, 64);
        if (lane >= off) s += t;
    }
    if (lane < SBLK) boff[lane] = s - v;
    if (lane == 63) ptr[N_NODES] = s;
}

__global__ void scan_final(const int* __restrict__ deg, const int* __restrict__ boff,
                           int* __restrict__ ptr, int* __restrict__ cursor) {
    __shared__ int wsum[4];
    const int tid = threadIdx.x;
    const int lane = tid & 63, wid = tid >> 6;
    int i0 = blockIdx.x * SCHUNK + tid * 8;
    int v[8]; int tsum = 0;
    #pragma unroll
    for (int j = 0; j < 8; ++j) {
        int i = i0 + j;
        v[j] = (i < N_NODES) ? deg[i] : 0;
        tsum += v[j];
    }
    int s = tsum;
    #pragma unroll
    for (int off = 1; off < 64; off <<= 1) {
        int t = __shfl_up(s, off, 64);
        if (lane >= off) s += t;
    }
    if (lane == 63) wsum[wid] = s;
    __syncthreads();
    int woff = 0;
    #pragma unroll
    for (int w = 0; w < 4; ++w) if (w < wid) woff += wsum[w];
    int excl = boff[blockIdx.x] + woff + (s - tsum);
    #pragma unroll
    for (int j = 0; j < 8; ++j) {
        int i = i0 + j;
        if (i < N_NODES) { ptr[i] = excl; cursor[i] = excl; }
        excl += v[j];
    }
}

__global__ void fill_kernel(const int* __restrict__ src, const int* __restrict__ dst,
                            int* __restrict__ cursor, int2* __restrict__ csr2) {
    int e = blockIdx.x * 256 + threadIdx.x;
    if (e < N_EDGES) {
        int d = dst[e];
        int slot = atomicAdd(&cursor[d], 1);
        csr2[slot] = make_int2(src[e], e);
    }
}

// direct gather segment-sum of eattr (f32), 4-wide pipelined, 8 lanes/node
__global__ void edge_sum(const int2* __restrict__ csr2, const int* __restrict__ ptr,
                         const float* __restrict__ eattr,
                         short* __restrict__ agge, float* __restrict__ degf) {
    int node = blockIdx.x * 32 + (threadIdx.x >> 3);
    int g = threadIdx.x & 7;
    if (node >= N_NODES) return;
    int s0 = ptr[node], s1 = ptr[node + 1];
    float4 a0 = make_float4(0.f,0.f,0.f,0.f), a1 = make_float4(0.f,0.f,0.f,0.f);
    int s = s0;
    int e0 = (s     < s1) ? csr2[s].y     : 0;
    int e1 = (s + 1 < s1) ? csr2[s + 1].y : 0;
    int e2 = (s + 2 < s1) ? csr2[s + 2].y : 0;
    int e3 = (s + 3 < s1) ? csr2[s + 3].y : 0;
    while (s + 4 <= s1) {
        float4 v0 = *reinterpret_cast<const float4*>(eattr + (size_t)e0 * ED + g * 4);
        float4 v1 = *reinterpret_cast<const float4*>(eattr + (size_t)e1 * ED + g * 4);
        float4 v2 = *reinterpret_cast<const float4*>(eattr + (size_t)e2 * ED + g * 4);
        float4 v3 = *reinterpret_cast<const float4*>(eattr + (size_t)e3 * ED + g * 4);
        s += 4;
        e0 = (s     < s1) ? csr2[s].y     : 0;
        e1 = (s + 1 < s1) ? csr2[s + 1].y : 0;
        e2 = (s + 2 < s1) ? csr2[s + 2].y : 0;
        e3 = (s + 3 < s1) ? csr2[s + 3].y : 0;
        a0.x += v0.x; a0.y += v0.y; a0.z += v0.z; a0.w += v0.w;
        a1.x += v1.x; a1.y += v1.y; a1.z += v1.z; a1.w += v1.w;
        a0.x += v2.x; a0.y += v2.y; a0.z += v2.z; a0.w += v2.w;
        a1.x += v3.x; a1.y += v3.y; a1.z += v3.z; a1.w += v3.w;
    }
    int rem = s1 - s;
    if (rem > 0) {
        float4 v = *reinterpret_cast<const float4*>(eattr + (size_t)e0 * ED + g * 4);
        a0.x += v.x; a0.y += v.y; a0.z += v.z; a0.w += v.w;
    }
    if (rem > 1) {
        float4 v = *reinterpret_cast<const float4*>(eattr + (size_t)e1 * ED + g * 4);
        a1.x += v.x; a1.y += v.y; a1.z += v.z; a1.w += v.w;
    }
    if (rem > 2) {
        float4 v = *reinterpret_cast<const float4*>(eattr + (size_t)e2 * ED + g * 4);
        a0.x += v.x; a0.y += v.y; a0.z += v.z; a0.w += v.w;
    }
    bf16x4 o;
    o[0] = f2b(a0.x + a1.x); o[1] = f2b(a0.y + a1.y);
    o[2] = f2b(a0.z + a1.z); o[3] = f2b(a0.w + a1.w);
    *reinterpret_cast<bf16x4*>(agge + (size_t)node * ED + g * 4) = o;
    if (g == 0) degf[node] = (float)(s1 - s0);
}

__global__ void wconv_kernel(const float* __restrict__ Wm, short* __restrict__ Wb) {
    int idx = blockIdx.x * 256 + threadIdx.x;
    if (idx < NL * HD * FAN) Wb[idx] = f2b(Wm[idx]);
}

__global__ void xconv_kernel(const float* __restrict__ x, const float* __restrict__ degf,
                             short* __restrict__ xb, short* __restrict__ xd) {
    int i4 = blockIdx.x * 256 + threadIdx.x;
    if (i4 >= N_NODES * (HD / 4)) return;
    int row = i4 >> 5;
    float d = degf[row];
    float4 v = reinterpret_cast<const float4*>(x)[i4];
    bf16x4 o, od;
    float vv[4] = {v.x, v.y, v.z, v.w};
    #pragma unroll
    for (int j = 0; j < 4; ++j) {
        short s = f2b(vv[j]);
        o[j] = s;
        od[j] = f2b(b2f(s) * d);
    }
    *reinterpret_cast<bf16x4*>(xb + (size_t)i4 * 4) = o;
    *reinterpret_cast<bf16x4*>(xd + (size_t)i4 * 4) = od;
}

// ---------- fused per-layer kernel: 4-wide gather (LDS) + MFMA GEMM ----------
// Block = 32 node-rows, 256 threads (4 waves; each wave owns a 32-col quarter).
#define TM 32

__global__ __launch_bounds__(256) void fused_layer(
    const int* __restrict__ ptr, const int2* __restrict__ csr2,
    const short* __restrict__ xprev,  // [NP][128] bf16 gather source (read-only)
    const short* __restrict__ xdeg,   // [NP][128] bf16 own-row read (in-place write OK)
    const short* __restrict__ agge,   // [NP][32]
    const float* __restrict__ degf,   // [NP]
    const short* __restrict__ Wb,     // [128][288]
    const float* __restrict__ b,      // [128]
    float* __restrict__ out_f32,      // last layer
    short* __restrict__ out_x,        // next-layer x (ping-pong, != xprev)
    short* __restrict__ out_xd,       // xdeg (in-place)
    int last)
{
    __shared__ char As[TM * 256];     // 8 KB: [32 rows][128 cols] bf16, swizzled
    const int tid = threadIdx.x;
    const int m0 = blockIdx.x * TM;

    // ---- phase 1: 4-wide pipelined gather-sum into LDS ----
    {
        const int ng = tid >> 4, g = tid & 15;
        #pragma unroll
        for (int i = 0; i < 2; ++i) {
            int row = i * 16 + ng;          // 0..31
            int node = m0 + row;
            float acc0[8] = {}, acc1[8] = {};
            if (node < N_NODES) {
                int s0 = ptr[node], s1 = ptr[node + 1];
                int s = s0;
                int i0 = (s     < s1) ? csr2[s].x     : 0;
                int i1 = (s + 1 < s1) ? csr2[s + 1].x : 0;
                int i2 = (s + 2 < s1) ? csr2[s + 2].x : 0;
                int i3 = (s + 3 < s1) ? csr2[s + 3].x : 0;
                while (s + 4 <= s1) {
                    bf16x8 v0 = *reinterpret_cast<const bf16x8*>(xprev + (size_t)i0 * HD + g * 8);
                    bf16x8 v1 = *reinterpret_cast<const bf16x8*>(xprev + (size_t)i1 * HD + g * 8);
                    bf16x8 v2 = *reinterpret_cast<const bf16x8*>(xprev + (size_t)i2 * HD + g * 8);
                    bf16x8 v3 = *reinterpret_cast<const bf16x8*>(xprev + (size_t)i3 * HD + g * 8);
                    s += 4;
                    i0 = (s     < s1) ? csr2[s].x     : 0;
                    i1 = (s + 1 < s1) ? csr2[s + 1].x : 0;
                    i2 = (s + 2 < s1) ? csr2[s + 2].x : 0;
                    i3 = (s + 3 < s1) ? csr2[s + 3].x : 0;
                    #pragma unroll
                    for (int j = 0; j < 8; ++j) acc0[j] += b2f(v0[j]);
                    #pragma unroll
                    for (int j = 0; j < 8; ++j) acc1[j] += b2f(v1[j]);
                    #pragma unroll
                    for (int j = 0; j < 8; ++j) acc0[j] += b2f(v2[j]);
                    #pragma unroll
                    for (int j = 0; j < 8; ++j) acc1[j] += b2f(v3[j]);
                }
                int rem = s1 - s;
                if (rem > 0) {
                    bf16x8 v = *reinterpret_cast<const bf16x8*>(xprev + (size_t)i0 * HD + g * 8);
                    #pragma unroll
                    for (int j = 0; j < 8; ++j) acc0[j] += b2f(v[j]);
                }
                if (rem > 1) {
                    bf16x8 v = *reinterpret_cast<const bf16x8*>(xprev + (size_t)i1 * HD + g * 8);
                    #pragma unroll
                    for (int j = 0; j < 8; ++j) acc1[j] += b2f(v[j]);
                }
                if (rem > 2) {
                    bf16x8 v = *reinterpret_cast<const bf16x8*>(xprev + (size_t)i2 * HD + g * 8);
                    #pragma unroll
                    for (int j = 0; j < 8; ++j) acc0[j] += b2f(v[j]);
                }
            }
            bf16x8 o;
            #pragma unroll
            for (int j = 0; j < 8; ++j) o[j] = f2b(acc0[j] + acc1[j]);
            int byte = row * 256 + g * 16;
            byte ^= (row & 7) << 4;         // bank swizzle
            *reinterpret_cast<bf16x8*>(As + byte) = o;
        }
    }
    __syncthreads();

    // ---- phase 2: MFMA (wave w owns cols [w*32, w*32+32)) ----
    const int w = tid >> 6, lane = tid & 63;
    const int l15 = lane & 15, lq = lane >> 4;
    const int kb = lq * 8;

    f32x4 acc[2][2];
    #pragma unroll
    for (int i = 0; i < 2; ++i)
        #pragma unroll
        for (int j = 0; j < 2; ++j) acc[i][j] = (f32x4){0.f, 0.f, 0.f, 0.f};

    // kt 0..3: A from LDS (agg_src)
    #pragma unroll
    for (int kt = 0; kt < 4; ++kt) {
        bf16x8 a[2], bf[2];
        #pragma unroll
        for (int mf = 0; mf < 2; ++mf) {
            int row = mf * 16 + l15;
            int byte = row * 256 + kt * 64 + kb * 2;
            byte ^= (row & 7) << 4;
            a[mf] = *reinterpret_cast<const bf16x8*>(As + byte);
        }
        #pragma unroll
        for (int nf = 0; nf < 2; ++nf) {
            int c = w * 32 + nf * 16 + l15;
            bf[nf] = *reinterpret_cast<const bf16x8*>(Wb + (size_t)c * FAN + kt * 32 + kb);
        }
        #pragma unroll
        for (int mf = 0; mf < 2; ++mf)
            #pragma unroll
            for (int nf = 0; nf < 2; ++nf)
                acc[mf][nf] = __builtin_amdgcn_mfma_f32_16x16x32_bf16(
                    a[mf], bf[nf], acc[mf][nf], 0, 0, 0);
    }
    // kt 4..7: A from xdeg (own rows); kt 8: agge
    #pragma unroll
    for (int kt = 4; kt < 9; ++kt) {
        bf16x8 a[2], bf[2];
        #pragma unroll
        for (int mf = 0; mf < 2; ++mf) {
            size_t arow = (size_t)(m0 + mf * 16 + l15);
            a[mf] = (kt < 8)
                ? *reinterpret_cast<const bf16x8*>(xdeg + arow * HD + (kt * 32 - 128) + kb)
                : *reinterpret_cast<const bf16x8*>(agge + arow * ED + kb);
        }
        #pragma unroll
        for (int nf = 0; nf < 2; ++nf) {
            int c = w * 32 + nf * 16 + l15;
            bf[nf] = *reinterpret_cast<const bf16x8*>(Wb + (size_t)c * FAN + kt * 32 + kb);
        }
        #pragma unroll
        for (int mf = 0; mf < 2; ++mf)
            #pragma unroll
            for (int nf = 0; nf < 2; ++nf)
                acc[mf][nf] = __builtin_amdgcn_mfma_f32_16x16x32_bf16(
                    a[mf], bf[nf], acc[mf][nf], 0, 0, 0);
    }

    // ---- epilogue ----
    #pragma unroll
    for (int mf = 0; mf < 2; ++mf) {
        int r0 = m0 + mf * 16 + lq * 4;
        float dg[4];
        #pragma unroll
        for (int j = 0; j < 4; ++j)
            dg[j] = (r0 + j < N_NODES) ? degf[r0 + j] : 0.f;
        #pragma unroll
        for (int nf = 0; nf < 2; ++nf) {
            int c = w * 32 + nf * 16 + l15;
            float bc = b[c];
            #pragma unroll
            for (int j = 0; j < 4; ++j) {
                int row = r0 + j;
                if (row >= N_NODES) continue;
                float v = acc[mf][nf][j] + dg[j] * bc;
                v = (v >= 0.f) ? v : 0.01f * v;
                if (last) {
                    v = (v >= 0.f) ? v : 0.01f * v;   // activate_last
                    out_f32[(size_t)row * HD + c] = v;
                } else {
                    short xb = f2b(v);
                    out_x[(size_t)row * HD + c] = xb;
                    out_xd[(size_t)row * HD + c] = f2b(b2f(xb) * dg[j]);
                }
            }
        }
    }
}

extern "C" void kernel_launch(void* const* d_in, const int* in_sizes, int n_in,
                              void* d_out, int out_size, void* d_ws, size_t ws_size,
                              hipStream_t stream) {
    const float* x_in  = (const float*)d_in[0];
    const int*   ei    = (const int*)d_in[1];
    const float* eattr = (const float*)d_in[2];
    const float* Wm    = (const float*)d_in[3];
    const float* bm    = (const float*)d_in[4];
    float* out = (float*)d_out;

    char* ws = (char*)d_ws;
    size_t off = 0;
    auto alloc = [&](size_t bytes) -> void* {
        void* p = ws + off;
        off = (off + bytes + 255) & ~(size_t)255;
        return p;
    };
    short* x0     = (short*)alloc((size_t)NP * HD * 2);
    short* x1     = (short*)alloc((size_t)NP * HD * 2);
    short* xdeg   = (short*)alloc((size_t)NP * HD * 2);
    short* agge   = (short*)alloc((size_t)NP * ED * 2);
    float* degf   = (float*)alloc((size_t)NP * 4);
    int*   deg    = (int*)alloc((size_t)N_NODES * 4);
    int*   ptr    = (int*)alloc((size_t)(N_NODES + 1) * 4);
    int*   cursor = (int*)alloc((size_t)N_NODES * 4);
    int2*  csr2   = (int2*)alloc((size_t)N_EDGES * 8);
    short* Wb     = (short*)alloc((size_t)NL * HD * FAN * 2);
    int*   bsum   = (int*)alloc((size_t)SBLK * 4);
    int*   boff   = (int*)alloc((size_t)SBLK * 4);

    const int* src = ei;
    const int* dst = ei + N_EDGES;

    hipMemsetAsync(deg, 0, (size_t)N_NODES * 4, stream);
    count_kernel<<<(N_EDGES + 255) / 256, 256, 0, stream>>>(dst, deg);
    scan_reduce<<<SBLK, 256, 0, stream>>>(deg, bsum);
    scan_mid<<<1, 64, 0, stream>>>(bsum, boff, ptr);
    scan_final<<<SBLK, 256, 0, stream>>>(deg, boff, ptr, cursor);
    fill_kernel<<<(N_EDGES + 255) / 256, 256, 0, stream>>>(src, dst, cursor, csr2);
    edge_sum<<<(N_NODES + 31) / 32, 256, 0, stream>>>(csr2, ptr, eattr, agge, degf);
    wconv_kernel<<<(NL * HD * FAN + 255) / 256, 256, 0, stream>>>(Wm, Wb);
    xconv_kernel<<<(N_NODES * (HD / 4) + 255) / 256, 256, 0, stream>>>(x_in, degf, x0, xdeg);

    short* xping[2] = {x0, x1};
    for (int l = 0; l < NL; ++l) {
        fused_layer<<<NP / TM, 256, 0, stream>>>(
            ptr, csr2, xping[l & 1], xdeg, agge, degf,
            Wb + (size_t)l * HD * FAN, bm + (size_t)l * HD,
            out, xping[(l + 1) & 1], xdeg, (l == NL - 1) ? 1 : 0);
    }
}